// Round 12
// baseline (518.857 us; speedup 1.0000x reference)
//
#include <hip/hip_runtime.h>
#include <hip/hip_bf16.h>

typedef __attribute__((ext_vector_type(8))) short bf16x8;   // 8 bf16 in 4 VGPRs
typedef __attribute__((ext_vector_type(4))) float f32x4;    // MFMA accumulator
typedef __attribute__((ext_vector_type(4))) int   i32x4;

#define NB 256
#define NT 200
#define NW 200
#define NE 768
#define NH 256
#define NEMB 32
#define KIN 800           // E + EMB
#define G3H 768           // 3*H
#define MROWS 51200       // B*T

__device__ __forceinline__ float bf2f(unsigned short h) {
    return __uint_as_float(((unsigned)h) << 16);
}
__device__ __forceinline__ unsigned short f2bf(float f) {
    unsigned u = __float_as_uint(f);
    u += 0x7fff + ((u >> 16) & 1);   // RNE
    return (unsigned short)(u >> 16);
}
__device__ __forceinline__ float sigm(float x) { return 1.0f / (1.0f + __expf(-x)); }
__device__ __forceinline__ float tanh_fast(float x) {
    float e = __expf(2.0f * x);
    return 1.0f - 2.0f / (e + 1.0f);
}

#if __has_builtin(__builtin_amdgcn_sdot4)
__device__ __forceinline__ int SDOT4(int a, int b, int c) {
    return __builtin_amdgcn_sdot4(a, b, c, false);
}
#else
__device__ __forceinline__ int SDOT4(int a, int b, int c) {   // exact fallback
    #pragma unroll
    for (int j = 0; j < 4; j++)
        c += (int)(signed char)(a >> (8 * j)) * (int)(signed char)(b >> (8 * j));
    return c;
}
#endif

// async global->LDS, 16 B/lane. LDS dest: wave-uniform base + lane*16.
__device__ __forceinline__ void gload16(const void* g, void* l) {
    __builtin_amdgcn_global_load_lds((const __attribute__((address_space(1))) unsigned int*)g,
                                     (__attribute__((address_space(3))) unsigned int*)l,
                                     16, 0, 0);
}

// ---------------------------------------------------------------------------
// prep1: A_bf16[51200][800] = [bf16(inputs) | bf16(emb_table[fix])],
//        W_ih -> bf16 [768][800], W_out -> bf16 TRANSPOSED [256][768],
//        biasC[768] = b_ih + (row<512 ? b_hh : 0), bias0[256] = 0
// ---------------------------------------------------------------------------
__global__ void prep1(const float* __restrict__ inputs, const int* __restrict__ fix_seq,
                      const float* __restrict__ emb, const float* __restrict__ Wih,
                      const float* __restrict__ Wout, const float* __restrict__ bih,
                      const float* __restrict__ bhh,
                      unsigned short* __restrict__ Abf, unsigned short* __restrict__ Wihbf,
                      unsigned short* __restrict__ WoutTbf, float* __restrict__ biasC,
                      float* __restrict__ bias0) {
    const long gid0 = (long)blockIdx.x * blockDim.x + threadIdx.x;
    if (gid0 < G3H) biasC[gid0] = bih[gid0] + (gid0 < 512 ? bhh[gid0] : 0.0f);
    if (gid0 < NH) bias0[gid0] = 0.0f;
    const long NA = (long)MROWS * 100;   // 8 cols per unit
    const long NWU = 768L * 100;
    const long NOU = 256L * 96;          // WoutT: 256 rows x 96 8-col chunks
    const long total = NA + NWU + NOU;
    for (long u = gid0; u < total; u += (long)gridDim.x * blockDim.x) {
        bf16x8 v;
        unsigned short* dst;
        if (u < NA) {
            long row = u / 100;
            int c8 = (int)(u % 100) * 8;
            const float* s;
            if (c8 < NE) {
                s = inputs + row * NE + c8;
            } else {
                int fx = fix_seq[row];
                s = emb + (long)fx * NEMB + (c8 - NE);
            }
            #pragma unroll
            for (int j = 0; j < 8; j++) v[j] = (short)f2bf(s[j]);
            dst = Abf + row * KIN + c8;
        } else if (u < NA + NWU) {
            long u2 = u - NA;
            long row = u2 / 100;
            int c8 = (int)(u2 % 100) * 8;
            const float* s = Wih + row * KIN + c8;
            #pragma unroll
            for (int j = 0; j < 8; j++) v[j] = (short)f2bf(s[j]);
            dst = Wihbf + row * KIN + c8;
        } else {
            long u3 = u - NA - NWU;
            long row = u3 / 96;          // h index 0..255
            int c8 = (int)(u3 % 96) * 8; // e chunk
            #pragma unroll
            for (int j = 0; j < 8; j++)
                v[j] = (short)f2bf(Wout[(long)(c8 + j) * NH + row]);   // transpose gather
            dst = WoutTbf + row * NE + c8;
        }
        *(bf16x8*)dst = v;
    }
}

// ---------------------------------------------------------------------------
// gemm_bt128: Out[M][N] (bf16) = A[M][K](bf16) * Bw[N][K](bf16)^T + bias
// BM=BN=128, BK=32, 256 threads. T3 2-phase dbuf + gload16 + XCD swizzle.
// ---------------------------------------------------------------------------
__global__ __launch_bounds__(256)
void gemm_bt128(const unsigned short* __restrict__ A,
                const unsigned short* __restrict__ Bw,
                const float* __restrict__ bias,
                unsigned short* __restrict__ Out,
                int M, int N, int K) {
    __shared__ unsigned short As[2][128 * 32];
    __shared__ unsigned short Bs[2][128 * 32];
    const int bid = (int)((blockIdx.x & 7) * (gridDim.x >> 3) + (blockIdx.x >> 3));
    const int nblk = N >> 7;
    const int m0 = (bid / nblk) << 7;
    const int n0 = (bid % nblk) << 7;
    const int tid = threadIdx.x;
    const int lane = tid & 63;
    const int wave = tid >> 6;
    const int wm = (wave >> 1) << 6;
    const int wn = (wave & 1) << 6;
    const int nk = K >> 5;

    const int srow = tid >> 2;
    const int sseg = (tid & 3) << 4;
    const char* gA0 = (const char*)(A + (long)(m0 + srow) * K) + sseg;        // rows 0-63
    const char* gA1 = (const char*)(A + (long)(m0 + 64 + srow) * K) + sseg;   // rows 64-127
    const char* gB0 = (const char*)(Bw + (long)(n0 + srow) * K) + sseg;
    const char* gB1 = (const char*)(Bw + (long)(n0 + 64 + srow) * K) + sseg;
    const int lofs = wave * 1024;

    f32x4 acc[4][4] = {};

    gload16(gA0, (char*)As[0] + lofs);
    gload16(gA1, (char*)As[0] + 4096 + lofs);
    gload16(gB0, (char*)Bs[0] + lofs);
    gload16(gB1, (char*)Bs[0] + 4096 + lofs);
    __syncthreads();                     // implicit vmcnt(0) drain: tile 0 ready

    int cur = 0;
    for (int kt = 0; kt < nk; kt++) {
        if (kt + 1 < nk) {               // stage NEXT tile (latency hides under MFMA)
            gload16(gA0 + (kt + 1) * 64, (char*)As[cur ^ 1] + lofs);
            gload16(gA1 + (kt + 1) * 64, (char*)As[cur ^ 1] + 4096 + lofs);
            gload16(gB0 + (kt + 1) * 64, (char*)Bs[cur ^ 1] + lofs);
            gload16(gB1 + (kt + 1) * 64, (char*)Bs[cur ^ 1] + 4096 + lofs);
        }
        bf16x8 af[4], bfr[4];
        #pragma unroll
        for (int mi = 0; mi < 4; mi++)
            af[mi] = *(const bf16x8*)((const char*)As[cur] +
                        (wm + mi * 16 + (lane & 15)) * 64 + ((lane >> 4) << 4));
        #pragma unroll
        for (int ni = 0; ni < 4; ni++)
            bfr[ni] = *(const bf16x8*)((const char*)Bs[cur] +
                        (wn + ni * 16 + (lane & 15)) * 64 + ((lane >> 4) << 4));
        #pragma unroll
        for (int mi = 0; mi < 4; mi++)
            #pragma unroll
            for (int ni = 0; ni < 4; ni++)
                acc[mi][ni] = __builtin_amdgcn_mfma_f32_16x16x32_bf16(
                                  af[mi], bfr[ni], acc[mi][ni], 0, 0, 0);
        __syncthreads();                 // drains vmcnt (next tile ready) + syncs reads
        cur ^= 1;
    }
    #pragma unroll
    for (int ni = 0; ni < 4; ni++) {
        const int col = n0 + wn + ni * 16 + (lane & 15);
        const float bv = bias[col];
        #pragma unroll
        for (int mi = 0; mi < 4; mi++) {
            const int row = m0 + wm + mi * 16 + ((lane >> 4) << 2);
            #pragma unroll
            for (int r = 0; r < 4; r++)
                Out[(long)(row + r) * N + col] = f2bf(acc[mi][ni][r] + bv);
        }
    }
}

// ---------------------------------------------------------------------------
// gru_fused: grid <=512 x 512 threads.
//   blocks [0,256):  int8 dot4 GRU recurrence (R7 structure, unchanged).
//   blocks [256,512): gemmG role — G = fwebf @ WoutT^T, persistent 128x128
//     tiles, two 4-wave sub-blocks per block, 2 rounds (uniform barriers).
//     gemmG has no dep on gru; its MFMA work runs in gru's 47% idle issue
//     slots (m114: MFMA+VALU waves co-schedule at max, not sum).
// 33 KB LDS, both paths <=128 VGPR -> 2 blocks/CU co-resident.
// ---------------------------------------------------------------------------
__global__ __launch_bounds__(512, 2)
__attribute__((amdgpu_waves_per_eu(2, 2)))
void gru_fused(const unsigned short* __restrict__ xg,   // [51200][768] bf16 (incl biasC)
               const float* __restrict__ Whh,            // [768][256] fp32
               const float* __restrict__ bhh,            // [768]
               const int* __restrict__ lengths,          // [256]
               unsigned short* __restrict__ hout,        // [51200][256] bf16 (masked)
               const unsigned short* __restrict__ Afw,   // fwebf [51200][768]
               const unsigned short* __restrict__ BwT,   // WoutT [256][768]
               unsigned short* __restrict__ G) {         // [51200][256] bf16
    __shared__ __align__(16) char smem[512 + 2 * 16384];
    const int tid = threadIdx.x;
    const int lane = tid & 63;
    const int wave = tid >> 6;               // 0..7

    if (blockIdx.x >= NB) {
        // ---- gemmG role ----
        const int roleblk = (int)blockIdx.x - NB;       // 0..255
        const int sub = tid >> 8;                        // 0/1
        const int tid4 = tid & 255;
        const int wave4 = tid4 >> 6;
        const int srow = tid4 >> 2;
        const int sseg = (tid4 & 3) << 4;
        char* base = smem + 512 + sub * 16384;
        char* lA0 = base + wave4 * 1024;
        char* lA1 = base + 4096 + wave4 * 1024;
        char* lB0 = base + 8192 + wave4 * 1024;
        char* lB1 = base + 12288 + wave4 * 1024;
        const int wm = (wave4 >> 1) << 6;
        const int wn = (wave4 & 1) << 6;

        for (int round = 0; round < 2; round++) {
            const int tile = roleblk * 2 + sub + round * 512;
            const bool active = tile < 800;              // 400 M-tiles x 2 N-tiles
            const int tc = active ? tile : 0;
            const int m0 = (tc >> 1) << 7;
            const int n0 = (tc & 1) << 7;
            const char* gA0 = (const char*)(Afw + (long)(m0 + srow) * NE) + sseg;
            const char* gA1 = (const char*)(Afw + (long)(m0 + 64 + srow) * NE) + sseg;
            const char* gB0 = (const char*)(BwT + (long)(n0 + srow) * NE) + sseg;
            const char* gB1 = (const char*)(BwT + (long)(n0 + 64 + srow) * NE) + sseg;
            f32x4 acc[4][4] = {};
            for (int kt = 0; kt < 24; kt++) {            // K = 768
                __syncthreads();
                if (active) {
                    gload16(gA0 + kt * 64, lA0);
                    gload16(gA1 + kt * 64, lA1);
                    gload16(gB0 + kt * 64, lB0);
                    gload16(gB1 + kt * 64, lB1);
                    asm volatile("s_waitcnt vmcnt(0)" ::: "memory");
                }
                __syncthreads();
                if (active) {
                    bf16x8 af[4], bfr[4];
                    #pragma unroll
                    for (int mi = 0; mi < 4; mi++)
                        af[mi] = *(const bf16x8*)(base +
                                    (wm + mi * 16 + (lane & 15)) * 64 + ((lane >> 4) << 4));
                    #pragma unroll
                    for (int ni = 0; ni < 4; ni++)
                        bfr[ni] = *(const bf16x8*)(base + 8192 +
                                    (wn + ni * 16 + (lane & 15)) * 64 + ((lane >> 4) << 4));
                    #pragma unroll
                    for (int mi = 0; mi < 4; mi++)
                        #pragma unroll
                        for (int ni = 0; ni < 4; ni++)
                            acc[mi][ni] = __builtin_amdgcn_mfma_f32_16x16x32_bf16(
                                              af[mi], bfr[ni], acc[mi][ni], 0, 0, 0);
                }
            }
            if (active) {
                #pragma unroll
                for (int ni = 0; ni < 4; ni++) {
                    const int col = n0 + wn + ni * 16 + (lane & 15);
                    #pragma unroll
                    for (int mi = 0; mi < 4; mi++) {
                        const int row = m0 + wm + mi * 16 + ((lane >> 4) << 2);
                        #pragma unroll
                        for (int r = 0; r < 4; r++)
                            G[(long)(row + r) * NH + col] = f2bf(acc[mi][ni][r]);
                    }
                }
            }
        }
        return;
    }

    // ---- GRU recurrence role (R7 structure, unchanged) ----
    unsigned char (*h8)[256] = (unsigned char (*)[256])smem;  // [2][256]
    const int b = blockIdx.x;
    const int col = wave * 32 + (lane & 31); // this thread's h-col
    const int kh = lane >> 5;                // K-half 0/1

    int W[3][32];
    #pragma unroll
    for (int g = 0; g < 3; g++) {
        const float* wr = Whh + (long)(g * 256 + col) * NH + kh * 128;
        #pragma unroll
        for (int d = 0; d < 32; d++) {
            const float4 f = *(const float4*)(wr + d * 4);
            unsigned pack = 0;
            #pragma unroll
            for (int j = 0; j < 4; j++) {
                const float fv = j == 0 ? f.x : j == 1 ? f.y : j == 2 ? f.z : f.w;
                int wq = (int)rintf(fv * 400.0f);
                wq = wq > 127 ? 127 : (wq < -127 ? -127 : wq);
                pack |= ((unsigned)(wq & 0xff)) << (8 * j);
            }
            W[g][d] = (int)pack;
        }
    }
    const float bhn = bhh[512 + col];        // n-gate b_hh (r,z folded into xg)
    const int len = lengths[b];
    if (tid < 128) ((unsigned*)h8)[tid] = 0u;   // zero both h buffers (512 B)

    const unsigned short* xrow = xg + (long)b * NT * G3H;
    unsigned short xv0 = xrow[col], xv1 = xrow[256 + col], xv2 = xrow[512 + col];
    float hp = 0.0f;
    const float ISC = 1.0f / (400.0f * 127.0f);
    const bool wlo = (lane < 32);

    asm volatile("s_waitcnt lgkmcnt(0)" ::: "memory");
    __builtin_amdgcn_sched_barrier(0);
    __builtin_amdgcn_s_barrier();
    __builtin_amdgcn_sched_barrier(0);

    for (int t = 0; t < NT; t++) {
        const unsigned char* hb = h8[(t + 1) & 1] + kh * 128;
        int p0a = 0, p0b = 0, p1a = 0, p1b = 0, p2a = 0, p2b = 0;
        #pragma unroll
        for (int r = 0; r < 8; r++) {
            const i32x4 hv = *(const i32x4*)(hb + r * 16);
            p0a = SDOT4(hv[0], W[0][r * 4 + 0], p0a);
            p1a = SDOT4(hv[0], W[1][r * 4 + 0], p1a);
            p2a = SDOT4(hv[0], W[2][r * 4 + 0], p2a);
            p0b = SDOT4(hv[1], W[0][r * 4 + 1], p0b);
            p1b = SDOT4(hv[1], W[1][r * 4 + 1], p1b);
            p2b = SDOT4(hv[1], W[2][r * 4 + 1], p2b);
            p0a = SDOT4(hv[2], W[0][r * 4 + 2], p0a);
            p1a = SDOT4(hv[2], W[1][r * 4 + 2], p1a);
            p2a = SDOT4(hv[2], W[2][r * 4 + 2], p2a);
            p0b = SDOT4(hv[3], W[0][r * 4 + 3], p0b);
            p1b = SDOT4(hv[3], W[1][r * 4 + 3], p1b);
            p2b = SDOT4(hv[3], W[2][r * 4 + 3], p2b);
        }
        int p0 = p0a + p0b, p1 = p1a + p1b, p2 = p2a + p2b;
        p0 += __shfl_xor(p0, 32);            // combine K-halves
        p1 += __shfl_xor(p1, 32);
        p2 += __shfl_xor(p2, 32);
        const float r = sigm(bf2f(xv0) + (float)p0 * ISC);
        const float z = sigm(bf2f(xv1) + (float)p1 * ISC);
        const float n = tanh_fast(bf2f(xv2) + r * ((float)p2 * ISC + bhn));
        hp = (1.0f - z) * n + z * hp;
        if (wlo) {
            h8[t & 1][col] = (unsigned char)((int)rintf(hp * 127.0f) & 0xff);
            hout[((long)b * NT + t) * NH + col] = (t < len) ? f2bf(hp) : (unsigned short)0;
        }
        if (t + 1 < NT) {
            const unsigned short* xn = xrow + (long)(t + 1) * G3H;
            xv0 = xn[col]; xv1 = xn[256 + col]; xv2 = xn[512 + col];
        }
        asm volatile("s_waitcnt lgkmcnt(0)" ::: "memory");
        __builtin_amdgcn_sched_barrier(0);
        __builtin_amdgcn_s_barrier();
        __builtin_amdgcn_sched_barrier(0);
    }
}

// ---------------------------------------------------------------------------
// prep2: fwe fp32 -> bf16, word_mask (sum|row| != 0), dvec[row] = fwe_row·b_out.
// ---------------------------------------------------------------------------
__global__ void prep2(const float* __restrict__ fwe, const float* __restrict__ bout,
                      unsigned short* __restrict__ fwebf,
                      unsigned char* __restrict__ wmask, float* __restrict__ dvec) {
    const int row = (int)((blockIdx.x * blockDim.x + threadIdx.x) >> 6);
    const int lane = threadIdx.x & 63;
    if (row >= MROWS) return;
    const float* s = fwe + (long)row * NE;
    unsigned short* d = fwebf + (long)row * NE;
    float asum = 0.0f, vdot = 0.0f;
    #pragma unroll
    for (int i = 0; i < 12; i++) {
        const float v = s[lane + i * 64];
        asum += fabsf(v);
        vdot += v * bout[lane + i * 64];
        d[lane + i * 64] = f2bf(v);
    }
    #pragma unroll
    for (int off = 32; off >= 1; off >>= 1) {
        asum += __shfl_xor(asum, off);
        vdot += __shfl_xor(vdot, off);
    }
    if (lane == 0) {
        wmask[row] = (asum != 0.0f) ? 1 : 0;
        dvec[row] = vdot;
    }
}

// ---------------------------------------------------------------------------
// logits_dur: wave per (b,t) row; only |w-fix|<=8 dots computed; dur fused.
// ---------------------------------------------------------------------------
__global__ __launch_bounds__(256)
void logits_dur(const unsigned short* __restrict__ Hrow,   // hout [51200][256]
                const unsigned short* __restrict__ G,      // [51200][256]
                const int* __restrict__ fix_seq,           // [51200]
                const unsigned char* __restrict__ wmask,   // [51200]
                const float* __restrict__ dvec,            // [51200]
                const float* __restrict__ Wdur, const float* __restrict__ bdur,
                float* __restrict__ out) {
    __shared__ float dots[4][20];
    const int wv = threadIdx.x >> 6;
    const int gwave = (int)blockIdx.x * 4 + wv;            // 0..51199 = b*200+t
    const int lane = threadIdx.x & 63;
    const int l16 = lane & 15;
    const int grp = lane >> 4;                              // 0..3
    const int b = gwave / NT;

    const unsigned short* hp = Hrow + (long)gwave * NH + l16 * 16;
    const bf16x8 h0 = *(const bf16x8*)hp;
    const bf16x8 h1 = *(const bf16x8*)(hp + 8);
    float hf[16];
    #pragma unroll
    for (int j = 0; j < 8; j++) { hf[j] = bf2f((unsigned short)h0[j]);
                                  hf[8 + j] = bf2f((unsigned short)h1[j]); }

    const int fix = fix_seq[gwave];
    const int wbase = fix - 8;

    if (fix != 0) {
        #pragma unroll
        for (int it = 0; it < 5; it++) {
            const int wi = it * 4 + grp;                    // 0..19 (17..19 unused)
            int w = wbase + wi;
            w = w < 0 ? 0 : (w > NW - 1 ? NW - 1 : w);      // clamp for safe load
            const unsigned short* gp = G + ((long)b * NW + w) * NH + l16 * 16;
            const bf16x8 g0 = *(const bf16x8*)gp;
            const bf16x8 g1 = *(const bf16x8*)(gp + 8);
            float p = 0.0f;
            #pragma unroll
            for (int j = 0; j < 8; j++) {
                p += hf[j] * bf2f((unsigned short)g0[j]);
                p += hf[8 + j] * bf2f((unsigned short)g1[j]);
            }
            p += __shfl_xor(p, 1); p += __shfl_xor(p, 2);
            p += __shfl_xor(p, 4); p += __shfl_xor(p, 8);
            if (l16 == 0 && wi < 17) dots[wv][wi] = p;
        }
    }
    float pd = 0.0f;
    #pragma unroll
    for (int j = 0; j < 16; j++) pd += hf[j] * Wdur[l16 * 16 + j];
    pd += __shfl_xor(pd, 1); pd += __shfl_xor(pd, 2);
    pd += __shfl_xor(pd, 4); pd += __shfl_xor(pd, 8);
    if (lane == 0) out[(long)NB * NT * NW + gwave] = pd + bdur[0];

    __syncthreads();

    if (lane < 50) {
        float4 o;
        #pragma unroll
        for (int c = 0; c < 4; c++) {
            const int w = lane * 4 + c;
            const int wi = w - wbase;
            const int wic = wi < 0 ? 0 : (wi > 16 ? 16 : wi);
            const bool ok = (fix != 0) && ((unsigned)wi < 17u) && (wmask[b * NW + w] != 0);
            const float val = dots[wv][wic] + dvec[b * NW + w];
            ((float*)&o)[c] = ok ? val : -1e9f;
        }
        *(float4*)(out + (long)gwave * NW + lane * 4) = o;
    }
}

// ---------------------------------------------------------------------------
extern "C" void kernel_launch(void* const* d_in, const int* in_sizes, int n_in,
                              void* d_out, int out_size, void* d_ws, size_t ws_size,
                              hipStream_t stream) {
    (void)in_sizes; (void)n_in; (void)out_size;
    const float* inputs  = (const float*)d_in[0];
    const int*   fix_seq = (const int*)d_in[1];
    const float* fwe     = (const float*)d_in[2];
    const int*   lengths = (const int*)d_in[3];
    const float* emb     = (const float*)d_in[5];
    const float* Wih     = (const float*)d_in[6];
    const float* bih     = (const float*)d_in[7];
    const float* Whh     = (const float*)d_in[8];
    const float* bhh     = (const float*)d_in[9];
    const float* Wout    = (const float*)d_in[10];
    const float* bout    = (const float*)d_in[11];
    const float* Wdur    = (const float*)d_in[12];
    const float* bdur    = (const float*)d_in[13];
    float* out = (float*)d_out;

    char* ws = (char*)d_ws;
    // region layout (bytes, all 256-aligned):
    //   R0 [0, 81,920,000)            A_bf16 [51200][800]  -> fwebf after gemm1
    //   R1 [81,920,000, +78,643,200)  xg_bf16 [51200][768] (G here in fallback)
    //   R2 [160,563,200, +26,214,400) hout_bf16 [51200][256]
    //   [186,777,600, +1,228,800)     W_ih bf16
    //   [188,006,400, +393,216)       W_outT bf16 [256][768]
    //   [188,399,616, +51,200)        word_mask u8
    //   [188,450,816, +3,072)         biasC f32 [768]
    //   [188,453,888, +204,800)       dvec f32 [51200]
    //   [188,658,688, +1,024)         bias0 f32 [256]
    //   [188,659,712, +26,214,400)    G bf16 (fused path only)
    unsigned short* Abf     = (unsigned short*)(ws);
    unsigned short* xgbf    = (unsigned short*)(ws + 81920000);
    unsigned short* hout    = (unsigned short*)(ws + 160563200);
    unsigned short* Wihbf   = (unsigned short*)(ws + 186777600);
    unsigned short* WoutTbf = (unsigned short*)(ws + 188006400);
    unsigned char*  wmask   = (unsigned char*)(ws + 188399616);
    float*          biasC   = (float*)(ws + 188450816);
    float*          dvec    = (float*)(ws + 188453888);
    float*          bias0   = (float*)(ws + 188658688);
    unsigned short* fwebf   = Abf;    // R0: A dead after gemm1

    const bool fused = (ws_size >= 214874112ull);
    unsigned short* Gbf = fused ? (unsigned short*)(ws + 188659712)
                                : xgbf;   // fallback: R1, xg dead after gru

    prep1<<<2048, 256, 0, stream>>>(inputs, fix_seq, emb, Wih, Wout, bih, bhh,
                                    Abf, Wihbf, WoutTbf, biasC, bias0);
    gemm_bt128<<<400 * 6, 256, 0, stream>>>(Abf, Wihbf, biasC, xgbf, MROWS, G3H, KIN);
    prep2<<<12800, 256, 0, stream>>>(fwe, bout, fwebf, wmask, dvec);
    if (fused) {
        // gemmG runs in the GRU's idle issue slots (no data dependency)
        gru_fused<<<512, 512, 0, stream>>>(xgbf, Whh, bhh, lengths, hout,
                                           fwebf, WoutTbf, Gbf);
    } else {
        gru_fused<<<256, 512, 0, stream>>>(xgbf, Whh, bhh, lengths, hout,
                                           fwebf, WoutTbf, Gbf);   // gru only
        gemm_bt128<<<400 * 2, 256, 0, stream>>>(fwebf, WoutTbf, bias0, Gbf,
                                                MROWS, NH, NE);
    }
    logits_dur<<<12800, 256, 0, stream>>>(hout, Gbf, fix_seq, wmask, dvec, Wdur, bdur, out);
}

// Round 13
// 501.236 us; speedup vs baseline: 1.0352x; 1.0352x over previous
//
#include <hip/hip_runtime.h>
#include <hip/hip_bf16.h>

typedef __attribute__((ext_vector_type(8))) short bf16x8;   // 8 bf16 in 4 VGPRs
typedef __attribute__((ext_vector_type(4))) float f32x4;    // MFMA accumulator
typedef __attribute__((ext_vector_type(4))) int   i32x4;

#define NB 256
#define NT 200
#define NW 200
#define NE 768
#define NH 256
#define NEMB 32
#define KIN 800           // E + EMB
#define G3H 768           // 3*H
#define MROWS 51200       // B*T

__device__ __forceinline__ float bf2f(unsigned short h) {
    return __uint_as_float(((unsigned)h) << 16);
}
__device__ __forceinline__ unsigned short f2bf(float f) {
    unsigned u = __float_as_uint(f);
    u += 0x7fff + ((u >> 16) & 1);   // RNE
    return (unsigned short)(u >> 16);
}
__device__ __forceinline__ float sigm(float x) { return 1.0f / (1.0f + __expf(-x)); }
__device__ __forceinline__ float tanh_fast(float x) {
    float e = __expf(2.0f * x);
    return 1.0f - 2.0f / (e + 1.0f);
}

#if __has_builtin(__builtin_amdgcn_sdot4)
__device__ __forceinline__ int SDOT4(int a, int b, int c) {
    return __builtin_amdgcn_sdot4(a, b, c, false);
}
#else
__device__ __forceinline__ int SDOT4(int a, int b, int c) {   // exact fallback
    #pragma unroll
    for (int j = 0; j < 4; j++)
        c += (int)(signed char)(a >> (8 * j)) * (int)(signed char)(b >> (8 * j));
    return c;
}
#endif

// async global->LDS, 16 B/lane. LDS dest: wave-uniform base + lane*16.
__device__ __forceinline__ void gload16(const void* g, void* l) {
    __builtin_amdgcn_global_load_lds((const __attribute__((address_space(1))) unsigned int*)g,
                                     (__attribute__((address_space(3))) unsigned int*)l,
                                     16, 0, 0);
}

// ---------------------------------------------------------------------------
// prep1: A_bf16[51200][800] = [bf16(inputs) | bf16(emb_table[fix])],
//        W_ih -> bf16 [768][800], W_out -> bf16 TRANSPOSED [256][768],
//        biasC[768] = b_ih + (row<512 ? b_hh : 0)
// ---------------------------------------------------------------------------
__global__ void prep1(const float* __restrict__ inputs, const int* __restrict__ fix_seq,
                      const float* __restrict__ emb, const float* __restrict__ Wih,
                      const float* __restrict__ Wout, const float* __restrict__ bih,
                      const float* __restrict__ bhh,
                      unsigned short* __restrict__ Abf, unsigned short* __restrict__ Wihbf,
                      unsigned short* __restrict__ WoutTbf, float* __restrict__ biasC) {
    const long gid0 = (long)blockIdx.x * blockDim.x + threadIdx.x;
    if (gid0 < G3H) biasC[gid0] = bih[gid0] + (gid0 < 512 ? bhh[gid0] : 0.0f);
    const long NA = (long)MROWS * 100;   // 8 cols per unit
    const long NWU = 768L * 100;
    const long NOU = 256L * 96;          // WoutT: 256 rows x 96 8-col chunks
    const long total = NA + NWU + NOU;
    for (long u = gid0; u < total; u += (long)gridDim.x * blockDim.x) {
        bf16x8 v;
        unsigned short* dst;
        if (u < NA) {
            long row = u / 100;
            int c8 = (int)(u % 100) * 8;
            const float* s;
            if (c8 < NE) {
                s = inputs + row * NE + c8;
            } else {
                int fx = fix_seq[row];
                s = emb + (long)fx * NEMB + (c8 - NE);
            }
            #pragma unroll
            for (int j = 0; j < 8; j++) v[j] = (short)f2bf(s[j]);
            dst = Abf + row * KIN + c8;
        } else if (u < NA + NWU) {
            long u2 = u - NA;
            long row = u2 / 100;
            int c8 = (int)(u2 % 100) * 8;
            const float* s = Wih + row * KIN + c8;
            #pragma unroll
            for (int j = 0; j < 8; j++) v[j] = (short)f2bf(s[j]);
            dst = Wihbf + row * KIN + c8;
        } else {
            long u3 = u - NA - NWU;
            long row = u3 / 96;          // h index 0..255
            int c8 = (int)(u3 % 96) * 8; // e chunk
            #pragma unroll
            for (int j = 0; j < 8; j++)
                v[j] = (short)f2bf(Wout[(long)(c8 + j) * NH + row]);   // transpose gather
            dst = WoutTbf + row * NE + c8;
        }
        *(bf16x8*)dst = v;
    }
}

// ---------------------------------------------------------------------------
// gemm_bt128: Out[M][N] (bf16) = A[M][K](bf16) * Bw[N][K](bf16)^T + bias
// BM=BN=128, BK=32, 256 threads. T3 2-phase dbuf + gload16 + XCD swizzle.
// (R11 form, unchanged.)
// ---------------------------------------------------------------------------
__global__ __launch_bounds__(256)
void gemm_bt128(const unsigned short* __restrict__ A,
                const unsigned short* __restrict__ Bw,
                const float* __restrict__ bias,
                unsigned short* __restrict__ Out,
                int M, int N, int K) {
    __shared__ unsigned short As[2][128 * 32];
    __shared__ unsigned short Bs[2][128 * 32];
    const int bid = (int)((blockIdx.x & 7) * (gridDim.x >> 3) + (blockIdx.x >> 3));
    const int nblk = N >> 7;
    const int m0 = (bid / nblk) << 7;
    const int n0 = (bid % nblk) << 7;
    const int tid = threadIdx.x;
    const int lane = tid & 63;
    const int wave = tid >> 6;
    const int wm = (wave >> 1) << 6;
    const int wn = (wave & 1) << 6;
    const int nk = K >> 5;

    const int srow = tid >> 2;
    const int sseg = (tid & 3) << 4;
    const char* gA0 = (const char*)(A + (long)(m0 + srow) * K) + sseg;        // rows 0-63
    const char* gA1 = (const char*)(A + (long)(m0 + 64 + srow) * K) + sseg;   // rows 64-127
    const char* gB0 = (const char*)(Bw + (long)(n0 + srow) * K) + sseg;
    const char* gB1 = (const char*)(Bw + (long)(n0 + 64 + srow) * K) + sseg;
    const int lofs = wave * 1024;

    f32x4 acc[4][4] = {};

    gload16(gA0, (char*)As[0] + lofs);
    gload16(gA1, (char*)As[0] + 4096 + lofs);
    gload16(gB0, (char*)Bs[0] + lofs);
    gload16(gB1, (char*)Bs[0] + 4096 + lofs);
    __syncthreads();                     // implicit vmcnt(0) drain: tile 0 ready

    int cur = 0;
    for (int kt = 0; kt < nk; kt++) {
        if (kt + 1 < nk) {               // stage NEXT tile (latency hides under MFMA)
            gload16(gA0 + (kt + 1) * 64, (char*)As[cur ^ 1] + lofs);
            gload16(gA1 + (kt + 1) * 64, (char*)As[cur ^ 1] + 4096 + lofs);
            gload16(gB0 + (kt + 1) * 64, (char*)Bs[cur ^ 1] + lofs);
            gload16(gB1 + (kt + 1) * 64, (char*)Bs[cur ^ 1] + 4096 + lofs);
        }
        bf16x8 af[4], bfr[4];
        #pragma unroll
        for (int mi = 0; mi < 4; mi++)
            af[mi] = *(const bf16x8*)((const char*)As[cur] +
                        (wm + mi * 16 + (lane & 15)) * 64 + ((lane >> 4) << 4));
        #pragma unroll
        for (int ni = 0; ni < 4; ni++)
            bfr[ni] = *(const bf16x8*)((const char*)Bs[cur] +
                        (wn + ni * 16 + (lane & 15)) * 64 + ((lane >> 4) << 4));
        #pragma unroll
        for (int mi = 0; mi < 4; mi++)
            #pragma unroll
            for (int ni = 0; ni < 4; ni++)
                acc[mi][ni] = __builtin_amdgcn_mfma_f32_16x16x32_bf16(
                                  af[mi], bfr[ni], acc[mi][ni], 0, 0, 0);
        __syncthreads();                 // drains vmcnt (next tile ready) + syncs reads
        cur ^= 1;
    }
    #pragma unroll
    for (int ni = 0; ni < 4; ni++) {
        const int col = n0 + wn + ni * 16 + (lane & 15);
        const float bv = bias[col];
        #pragma unroll
        for (int mi = 0; mi < 4; mi++) {
            const int row = m0 + wm + mi * 16 + ((lane >> 4) << 2);
            #pragma unroll
            for (int r = 0; r < 4; r++)
                Out[(long)(row + r) * N + col] = f2bf(acc[mi][ni][r] + bv);
        }
    }
}

// ---------------------------------------------------------------------------
// gemmG_f32: G[M][256] = fwe[M][768](fp32) @ WoutT[256][768](bf16)^T, PLUS
// per-row reductions folded into the A staging pass (prep2 eliminated):
//   wmask[row] = (sum|fwe[row]|) != 0,  dvec[row] = fwe[row]·b_out.
// A is reg-staged (fp32 load -> bf16 convert -> ds_write); B via gload16.
// Each block covers full K for its 128 rows -> reductions complete in-block.
// The two N-tile blocks compute identical sums (same order) -> benign dup.
// ---------------------------------------------------------------------------
__global__ __launch_bounds__(256)
void gemmG_f32(const float* __restrict__ fwe,           // [51200][768] fp32
               const unsigned short* __restrict__ BwT,  // WoutT [256][768] bf16
               const float* __restrict__ bout,          // [768]
               unsigned short* __restrict__ G,          // [51200][256] bf16
               unsigned char* __restrict__ wmask,       // [51200]
               float* __restrict__ dvec) {              // [51200]
    __shared__ unsigned short As[128 * 32];
    __shared__ unsigned short Bs[128 * 32];
    __shared__ float Bo[G3H];
    const int bid = (int)((blockIdx.x & 7) * (gridDim.x >> 3) + (blockIdx.x >> 3));
    const int m0 = (bid >> 1) << 7;      // 400 M-tiles
    const int n0 = (bid & 1) << 7;       // 2 N-tiles
    const int tid = threadIdx.x;
    const int lane = tid & 63;
    const int wave = tid >> 6;
    const int wm = (wave >> 1) << 6;
    const int wn = (wave & 1) << 6;

    // B staging (gload16): same map as gemm_bt128
    const int srow = tid >> 2;
    const int sseg = (tid & 3) << 4;
    const char* gB0 = (const char*)(BwT + (long)(n0 + srow) * NE) + sseg;
    const char* gB1 = (const char*)(BwT + (long)(n0 + 64 + srow) * NE) + sseg;
    char* lB0 = (char*)Bs + wave * 1024;
    char* lB1 = (char*)Bs + 4096 + wave * 1024;

    // A reg-staging: thread -> (row = tid>>1, 16-wide k-half = tid&1)
    const int arow = tid >> 1;
    const int akh = tid & 1;
    const float* aptr = fwe + (long)(m0 + arow) * NE + akh * 16;
    char* la = (char*)As + arow * 64 + akh * 32;

    for (int i = tid; i < G3H; i += 256) Bo[i] = bout[i];

    float4 fa0 = *(const float4*)(aptr);
    float4 fa1 = *(const float4*)(aptr + 4);
    float4 fa2 = *(const float4*)(aptr + 8);
    float4 fa3 = *(const float4*)(aptr + 12);

    f32x4 acc[4][4] = {};
    float asum = 0.0f, vdot = 0.0f;

    __syncthreads();                     // Bo visible

    for (int kt = 0; kt < 24; kt++) {    // K = 768
        __syncthreads();                 // previous tile's LDS reads complete
        gload16(gB0 + kt * 64, lB0);
        gload16(gB1 + kt * 64, lB1);
        // convert + write A slice, fold reductions (fp32, pre-conversion)
        const float* bo = Bo + kt * 32 + akh * 16;
        const float4 b0 = *(const float4*)(bo);
        const float4 b1 = *(const float4*)(bo + 4);
        const float4 b2 = *(const float4*)(bo + 8);
        const float4 b3 = *(const float4*)(bo + 12);
        asum += fabsf(fa0.x) + fabsf(fa0.y) + fabsf(fa0.z) + fabsf(fa0.w)
              + fabsf(fa1.x) + fabsf(fa1.y) + fabsf(fa1.z) + fabsf(fa1.w)
              + fabsf(fa2.x) + fabsf(fa2.y) + fabsf(fa2.z) + fabsf(fa2.w)
              + fabsf(fa3.x) + fabsf(fa3.y) + fabsf(fa3.z) + fabsf(fa3.w);
        vdot += fa0.x * b0.x + fa0.y * b0.y + fa0.z * b0.z + fa0.w * b0.w
              + fa1.x * b1.x + fa1.y * b1.y + fa1.z * b1.z + fa1.w * b1.w
              + fa2.x * b2.x + fa2.y * b2.y + fa2.z * b2.z + fa2.w * b2.w
              + fa3.x * b3.x + fa3.y * b3.y + fa3.z * b3.z + fa3.w * b3.w;
        bf16x8 v0, v1;
        v0[0] = (short)f2bf(fa0.x); v0[1] = (short)f2bf(fa0.y);
        v0[2] = (short)f2bf(fa0.z); v0[3] = (short)f2bf(fa0.w);
        v0[4] = (short)f2bf(fa1.x); v0[5] = (short)f2bf(fa1.y);
        v0[6] = (short)f2bf(fa1.z); v0[7] = (short)f2bf(fa1.w);
        v1[0] = (short)f2bf(fa2.x); v1[1] = (short)f2bf(fa2.y);
        v1[2] = (short)f2bf(fa2.z); v1[3] = (short)f2bf(fa2.w);
        v1[4] = (short)f2bf(fa3.x); v1[5] = (short)f2bf(fa3.y);
        v1[6] = (short)f2bf(fa3.z); v1[7] = (short)f2bf(fa3.w);
        *(bf16x8*)la = v0;
        *(bf16x8*)(la + 16) = v1;
        asm volatile("s_waitcnt vmcnt(0)" ::: "memory");   // B landed
        __syncthreads();                 // all stages visible (incl. ds_writes)
        if (kt + 1 < 24) {               // A prefetch hides under MFMA phase
            const float* ap = aptr + (kt + 1) * 32;
            fa0 = *(const float4*)(ap);
            fa1 = *(const float4*)(ap + 4);
            fa2 = *(const float4*)(ap + 8);
            fa3 = *(const float4*)(ap + 12);
        }
        bf16x8 af[4], bfr[4];
        #pragma unroll
        for (int mi = 0; mi < 4; mi++)
            af[mi] = *(const bf16x8*)((const char*)As +
                        (wm + mi * 16 + (lane & 15)) * 64 + ((lane >> 4) << 4));
        #pragma unroll
        for (int ni = 0; ni < 4; ni++)
            bfr[ni] = *(const bf16x8*)((const char*)Bs +
                        (wn + ni * 16 + (lane & 15)) * 64 + ((lane >> 4) << 4));
        #pragma unroll
        for (int mi = 0; mi < 4; mi++)
            #pragma unroll
            for (int ni = 0; ni < 4; ni++)
                acc[mi][ni] = __builtin_amdgcn_mfma_f32_16x16x32_bf16(
                                  af[mi], bfr[ni], acc[mi][ni], 0, 0, 0);
    }
    // reductions: combine the row's two k-half threads (t, t^1 in same wave)
    asum += __shfl_xor(asum, 1);
    vdot += __shfl_xor(vdot, 1);
    if (akh == 0) {
        wmask[m0 + arow] = (asum != 0.0f) ? 1 : 0;
        dvec[m0 + arow] = vdot;
    }
    // G epilogue (no bias)
    #pragma unroll
    for (int ni = 0; ni < 4; ni++) {
        const int col = n0 + wn + ni * 16 + (lane & 15);
        #pragma unroll
        for (int mi = 0; mi < 4; mi++) {
            const int row = m0 + wm + mi * 16 + ((lane >> 4) << 2);
            #pragma unroll
            for (int r = 0; r < 4; r++)
                G[(long)(row + r) * NH + col] = f2bf(acc[mi][ni][r]);
        }
    }
}

// ---------------------------------------------------------------------------
// gru_scan: 256 blocks (1 batch each), 512 threads (8 waves, 2/SIMD).
// Pure-VALU int8 GEMV via v_dot4_i32_i8 (R7/R8 structure, unchanged).
// ---------------------------------------------------------------------------
__global__ __launch_bounds__(512, 2)
__attribute__((amdgpu_waves_per_eu(2, 2)))
void gru_scan(const unsigned short* __restrict__ xg,   // [51200][768] bf16 (incl biasC)
              const float* __restrict__ Whh,            // [768][256] fp32
              const float* __restrict__ bhh,            // [768]
              const int* __restrict__ lengths,          // [256]
              unsigned short* __restrict__ hout) {      // [51200][256] bf16 (masked)
    __shared__ __align__(16) unsigned char h8[2][256];  // int8 h double buffer
    const int tid = threadIdx.x;
    const int lane = tid & 63;
    const int wave = tid >> 6;               // 0..7
    const int b = blockIdx.x;
    const int col = wave * 32 + (lane & 31); // this thread's h-col
    const int kh = lane >> 5;                // K-half 0/1

    int W[3][32];
    #pragma unroll
    for (int g = 0; g < 3; g++) {
        const float* wr = Whh + (long)(g * 256 + col) * NH + kh * 128;
        #pragma unroll
        for (int d = 0; d < 32; d++) {
            const float4 f = *(const float4*)(wr + d * 4);
            unsigned pack = 0;
            #pragma unroll
            for (int j = 0; j < 4; j++) {
                const float fv = j == 0 ? f.x : j == 1 ? f.y : j == 2 ? f.z : f.w;
                int wq = (int)rintf(fv * 400.0f);
                wq = wq > 127 ? 127 : (wq < -127 ? -127 : wq);
                pack |= ((unsigned)(wq & 0xff)) << (8 * j);
            }
            W[g][d] = (int)pack;
        }
    }
    const float bhn = bhh[512 + col];        // n-gate b_hh (r,z folded into xg)
    const int len = lengths[b];
    if (tid < 128) ((unsigned*)h8)[tid] = 0u;   // zero both h buffers (512 B)

    const unsigned short* xrow = xg + (long)b * NT * G3H;
    unsigned short xv0 = xrow[col], xv1 = xrow[256 + col], xv2 = xrow[512 + col];
    float hp = 0.0f;
    const float ISC = 1.0f / (400.0f * 127.0f);
    const bool wlo = (lane < 32);

    asm volatile("s_waitcnt lgkmcnt(0)" ::: "memory");
    __builtin_amdgcn_sched_barrier(0);
    __builtin_amdgcn_s_barrier();
    __builtin_amdgcn_sched_barrier(0);

    for (int t = 0; t < NT; t++) {
        const unsigned char* hb = h8[(t + 1) & 1] + kh * 128;
        int p0a = 0, p0b = 0, p1a = 0, p1b = 0, p2a = 0, p2b = 0;
        #pragma unroll
        for (int r = 0; r < 8; r++) {
            const i32x4 hv = *(const i32x4*)(hb + r * 16);
            p0a = SDOT4(hv[0], W[0][r * 4 + 0], p0a);
            p1a = SDOT4(hv[0], W[1][r * 4 + 0], p1a);
            p2a = SDOT4(hv[0], W[2][r * 4 + 0], p2a);
            p0b = SDOT4(hv[1], W[0][r * 4 + 1], p0b);
            p1b = SDOT4(hv[1], W[1][r * 4 + 1], p1b);
            p2b = SDOT4(hv[1], W[2][r * 4 + 1], p2b);
            p0a = SDOT4(hv[2], W[0][r * 4 + 2], p0a);
            p1a = SDOT4(hv[2], W[1][r * 4 + 2], p1a);
            p2a = SDOT4(hv[2], W[2][r * 4 + 2], p2a);
            p0b = SDOT4(hv[3], W[0][r * 4 + 3], p0b);
            p1b = SDOT4(hv[3], W[1][r * 4 + 3], p1b);
            p2b = SDOT4(hv[3], W[2][r * 4 + 3], p2b);
        }
        int p0 = p0a + p0b, p1 = p1a + p1b, p2 = p2a + p2b;
        p0 += __shfl_xor(p0, 32);            // combine K-halves
        p1 += __shfl_xor(p1, 32);
        p2 += __shfl_xor(p2, 32);
        const float r = sigm(bf2f(xv0) + (float)p0 * ISC);
        const float z = sigm(bf2f(xv1) + (float)p1 * ISC);
        const float n = tanh_fast(bf2f(xv2) + r * ((float)p2 * ISC + bhn));
        hp = (1.0f - z) * n + z * hp;
        if (wlo) {
            h8[t & 1][col] = (unsigned char)((int)rintf(hp * 127.0f) & 0xff);
            hout[((long)b * NT + t) * NH + col] = (t < len) ? f2bf(hp) : (unsigned short)0;
        }
        if (t + 1 < NT) {
            const unsigned short* xn = xrow + (long)(t + 1) * G3H;
            xv0 = xn[col]; xv1 = xn[256 + col]; xv2 = xn[512 + col];
        }
        asm volatile("s_waitcnt lgkmcnt(0)" ::: "memory");
        __builtin_amdgcn_sched_barrier(0);
        __builtin_amdgcn_s_barrier();
        __builtin_amdgcn_sched_barrier(0);
    }
}

// ---------------------------------------------------------------------------
// logits_dur: wave per (b,t) row; only |w-fix|<=8 dots computed; dur fused.
// (R11 form, unchanged.)
// ---------------------------------------------------------------------------
__global__ __launch_bounds__(256)
void logits_dur(const unsigned short* __restrict__ Hrow,   // hout [51200][256]
                const unsigned short* __restrict__ G,      // [51200][256]
                const int* __restrict__ fix_seq,           // [51200]
                const unsigned char* __restrict__ wmask,   // [51200]
                const float* __restrict__ dvec,            // [51200]
                const float* __restrict__ Wdur, const float* __restrict__ bdur,
                float* __restrict__ out) {
    __shared__ float dots[4][20];
    const int wv = threadIdx.x >> 6;
    const int gwave = (int)blockIdx.x * 4 + wv;            // 0..51199 = b*200+t
    const int lane = threadIdx.x & 63;
    const int l16 = lane & 15;
    const int grp = lane >> 4;                              // 0..3
    const int b = gwave / NT;

    const unsigned short* hp = Hrow + (long)gwave * NH + l16 * 16;
    const bf16x8 h0 = *(const bf16x8*)hp;
    const bf16x8 h1 = *(const bf16x8*)(hp + 8);
    float hf[16];
    #pragma unroll
    for (int j = 0; j < 8; j++) { hf[j] = bf2f((unsigned short)h0[j]);
                                  hf[8 + j] = bf2f((unsigned short)h1[j]); }

    const int fix = fix_seq[gwave];
    const int wbase = fix - 8;

    if (fix != 0) {
        #pragma unroll
        for (int it = 0; it < 5; it++) {
            const int wi = it * 4 + grp;                    // 0..19 (17..19 unused)
            int w = wbase + wi;
            w = w < 0 ? 0 : (w > NW - 1 ? NW - 1 : w);      // clamp for safe load
            const unsigned short* gp = G + ((long)b * NW + w) * NH + l16 * 16;
            const bf16x8 g0 = *(const bf16x8*)gp;
            const bf16x8 g1 = *(const bf16x8*)(gp + 8);
            float p = 0.0f;
            #pragma unroll
            for (int j = 0; j < 8; j++) {
                p += hf[j] * bf2f((unsigned short)g0[j]);
                p += hf[8 + j] * bf2f((unsigned short)g1[j]);
            }
            p += __shfl_xor(p, 1); p += __shfl_xor(p, 2);
            p += __shfl_xor(p, 4); p += __shfl_xor(p, 8);
            if (l16 == 0 && wi < 17) dots[wv][wi] = p;
        }
    }
    float pd = 0.0f;
    #pragma unroll
    for (int j = 0; j < 16; j++) pd += hf[j] * Wdur[l16 * 16 + j];
    pd += __shfl_xor(pd, 1); pd += __shfl_xor(pd, 2);
    pd += __shfl_xor(pd, 4); pd += __shfl_xor(pd, 8);
    if (lane == 0) out[(long)NB * NT * NW + gwave] = pd + bdur[0];

    __syncthreads();

    if (lane < 50) {
        float4 o;
        #pragma unroll
        for (int c = 0; c < 4; c++) {
            const int w = lane * 4 + c;
            const int wi = w - wbase;
            const int wic = wi < 0 ? 0 : (wi > 16 ? 16 : wi);
            const bool ok = (fix != 0) && ((unsigned)wi < 17u) && (wmask[b * NW + w] != 0);
            const float val = dots[wv][wic] + dvec[b * NW + w];
            ((float*)&o)[c] = ok ? val : -1e9f;
        }
        *(float4*)(out + (long)gwave * NW + lane * 4) = o;
    }
}

// ---------------------------------------------------------------------------
extern "C" void kernel_launch(void* const* d_in, const int* in_sizes, int n_in,
                              void* d_out, int out_size, void* d_ws, size_t ws_size,
                              hipStream_t stream) {
    (void)in_sizes; (void)n_in; (void)out_size; (void)ws_size;
    const float* inputs  = (const float*)d_in[0];
    const int*   fix_seq = (const int*)d_in[1];
    const float* fwe     = (const float*)d_in[2];
    const int*   lengths = (const int*)d_in[3];
    const float* emb     = (const float*)d_in[5];
    const float* Wih     = (const float*)d_in[6];
    const float* bih     = (const float*)d_in[7];
    const float* Whh     = (const float*)d_in[8];
    const float* bhh     = (const float*)d_in[9];
    const float* Wout    = (const float*)d_in[10];
    const float* bout    = (const float*)d_in[11];
    const float* Wdur    = (const float*)d_in[12];
    const float* bdur    = (const float*)d_in[13];
    float* out = (float*)d_out;

    char* ws = (char*)d_ws;
    // region layout (bytes, all 256-aligned):
    //   R0 [0, 81,920,000)            A_bf16 [51200][800]  -> G [51200][256] after gemm1
    //   R1 [81,920,000, +78,643,200)  xg_bf16 [51200][768]
    //   R2 [160,563,200, +26,214,400) hout_bf16 [51200][256]
    //   [186,777,600, +1,228,800)     W_ih bf16
    //   [188,006,400, +393,216)       W_outT bf16 [256][768]
    //   [188,399,616, +51,200)        word_mask u8
    //   [188,450,816, +3,072)         biasC f32 [768]
    //   [188,453,888, +204,800)       dvec f32 [51200]
    unsigned short* Abf     = (unsigned short*)(ws);
    unsigned short* xgbf    = (unsigned short*)(ws + 81920000);
    unsigned short* hout    = (unsigned short*)(ws + 160563200);
    unsigned short* Wihbf   = (unsigned short*)(ws + 186777600);
    unsigned short* WoutTbf = (unsigned short*)(ws + 188006400);
    unsigned char*  wmask   = (unsigned char*)(ws + 188399616);
    float*          biasC   = (float*)(ws + 188450816);
    float*          dvec    = (float*)(ws + 188453888);
    unsigned short* Gbf     = Abf;    // R0: A dead after gemm1

    prep1<<<2048, 256, 0, stream>>>(inputs, fix_seq, emb, Wih, Wout, bih, bhh,
                                    Abf, Wihbf, WoutTbf, biasC);
    gemm_bt128<<<400 * 6, 256, 0, stream>>>(Abf, Wihbf, biasC, xgbf, MROWS, G3H, KIN);
    gemmG_f32<<<800, 256, 0, stream>>>(fwe, WoutTbf, bout, Gbf, wmask, dvec);
    gru_scan<<<256, 512, 0, stream>>>(xgbf, Whh, bhh, lengths, hout);
    logits_dur<<<12800, 256, 0, stream>>>(hout, Gbf, fix_seq, wmask, dvec, Wdur, bdur, out);
}

// Round 14
// 499.897 us; speedup vs baseline: 1.0379x; 1.0027x over previous
//
#include <hip/hip_runtime.h>
#include <hip/hip_bf16.h>

typedef __attribute__((ext_vector_type(8))) short bf16x8;   // 8 bf16 in 4 VGPRs
typedef __attribute__((ext_vector_type(4))) float f32x4;    // MFMA accumulator
typedef __attribute__((ext_vector_type(4))) int   i32x4;

#define NB 256
#define NT 200
#define NW 200
#define NE 768
#define NH 256
#define NEMB 32
#define KIN 800           // E + EMB
#define G3H 768           // 3*H
#define MROWS 51200       // B*T

__device__ __forceinline__ float bf2f(unsigned short h) {
    return __uint_as_float(((unsigned)h) << 16);
}
__device__ __forceinline__ unsigned short f2bf(float f) {
    unsigned u = __float_as_uint(f);
    u += 0x7fff + ((u >> 16) & 1);   // RNE
    return (unsigned short)(u >> 16);
}
__device__ __forceinline__ float sigm(float x) { return 1.0f / (1.0f + __expf(-x)); }
__device__ __forceinline__ float tanh_fast(float x) {
    float e = __expf(2.0f * x);
    return 1.0f - 2.0f / (e + 1.0f);
}

#if __has_builtin(__builtin_amdgcn_sdot4)
__device__ __forceinline__ int SDOT4(int a, int b, int c) {
    return __builtin_amdgcn_sdot4(a, b, c, false);
}
#else
__device__ __forceinline__ int SDOT4(int a, int b, int c) {   // exact fallback
    #pragma unroll
    for (int j = 0; j < 4; j++)
        c += (int)(signed char)(a >> (8 * j)) * (int)(signed char)(b >> (8 * j));
    return c;
}
#endif

// async global->LDS, 16 B/lane. LDS dest: wave-uniform base + lane*16.
__device__ __forceinline__ void gload16(const void* g, void* l) {
    __builtin_amdgcn_global_load_lds((const __attribute__((address_space(1))) unsigned int*)g,
                                     (__attribute__((address_space(3))) unsigned int*)l,
                                     16, 0, 0);
}

// ---------------------------------------------------------------------------
// prep1: A_bf16[51200][800] = [bf16(inputs) | bf16(emb_table[fix])],
//        W_ih -> bf16 [768][800], W_out -> bf16 TRANSPOSED [256][768],
//        biasC[768] = b_ih + (row<512 ? b_hh : 0)
// ---------------------------------------------------------------------------
__global__ void prep1(const float* __restrict__ inputs, const int* __restrict__ fix_seq,
                      const float* __restrict__ emb, const float* __restrict__ Wih,
                      const float* __restrict__ Wout, const float* __restrict__ bih,
                      const float* __restrict__ bhh,
                      unsigned short* __restrict__ Abf, unsigned short* __restrict__ Wihbf,
                      unsigned short* __restrict__ WoutTbf, float* __restrict__ biasC) {
    const long gid0 = (long)blockIdx.x * blockDim.x + threadIdx.x;
    if (gid0 < G3H) biasC[gid0] = bih[gid0] + (gid0 < 512 ? bhh[gid0] : 0.0f);
    const long NA = (long)MROWS * 100;   // 8 cols per unit
    const long NWU = 768L * 100;
    const long NOU = 256L * 96;          // WoutT: 256 rows x 96 8-col chunks
    const long total = NA + NWU + NOU;
    for (long u = gid0; u < total; u += (long)gridDim.x * blockDim.x) {
        bf16x8 v;
        unsigned short* dst;
        if (u < NA) {
            long row = u / 100;
            int c8 = (int)(u % 100) * 8;
            const float* s;
            if (c8 < NE) {
                s = inputs + row * NE + c8;
            } else {
                int fx = fix_seq[row];
                s = emb + (long)fx * NEMB + (c8 - NE);
            }
            #pragma unroll
            for (int j = 0; j < 8; j++) v[j] = (short)f2bf(s[j]);
            dst = Abf + row * KIN + c8;
        } else if (u < NA + NWU) {
            long u2 = u - NA;
            long row = u2 / 100;
            int c8 = (int)(u2 % 100) * 8;
            const float* s = Wih + row * KIN + c8;
            #pragma unroll
            for (int j = 0; j < 8; j++) v[j] = (short)f2bf(s[j]);
            dst = Wihbf + row * KIN + c8;
        } else {
            long u3 = u - NA - NWU;
            long row = u3 / 96;          // h index 0..255
            int c8 = (int)(u3 % 96) * 8; // e chunk
            #pragma unroll
            for (int j = 0; j < 8; j++)
                v[j] = (short)f2bf(Wout[(long)(c8 + j) * NH + row]);   // transpose gather
            dst = WoutTbf + row * NE + c8;
        }
        *(bf16x8*)dst = v;
    }
}

// ---------------------------------------------------------------------------
// gemm_bt128: Out[M][N] (bf16) = A[M][K](bf16) * Bw[N][K](bf16)^T + bias
// BM=BN=128, BK=32, 256 threads. T4 counted-vmcnt pipeline:
//   stage buf[cur^1] -> s_waitcnt vmcnt(4)   (only PREVIOUS tile's loads;
//   the 4 just-issued loads stay in flight ACROSS the barrier and complete
//   under the MFMAs) -> raw s_barrier -> ds_read+MFMA buf[cur] ->
//   lgkmcnt(0)+s_barrier (WAR: reads retired before next overwrite).
// No vmcnt(0) drain in the main loop (m135 FIFO semantics: vmcnt(4) waits
// exactly for the oldest 4). gload16 + XCD-bijective swizzle as before.
// ---------------------------------------------------------------------------
__global__ __launch_bounds__(256)
void gemm_bt128(const unsigned short* __restrict__ A,
                const unsigned short* __restrict__ Bw,
                const float* __restrict__ bias,
                unsigned short* __restrict__ Out,
                int M, int N, int K) {
    __shared__ unsigned short As[2][128 * 32];
    __shared__ unsigned short Bs[2][128 * 32];
    const int bid = (int)((blockIdx.x & 7) * (gridDim.x >> 3) + (blockIdx.x >> 3));
    const int nblk = N >> 7;
    const int m0 = (bid / nblk) << 7;
    const int n0 = (bid % nblk) << 7;
    const int tid = threadIdx.x;
    const int lane = tid & 63;
    const int wave = tid >> 6;
    const int wm = (wave >> 1) << 6;
    const int wn = (wave & 1) << 6;
    const int nk = K >> 5;

    const int srow = tid >> 2;
    const int sseg = (tid & 3) << 4;
    const char* gA0 = (const char*)(A + (long)(m0 + srow) * K) + sseg;        // rows 0-63
    const char* gA1 = (const char*)(A + (long)(m0 + 64 + srow) * K) + sseg;   // rows 64-127
    const char* gB0 = (const char*)(Bw + (long)(n0 + srow) * K) + sseg;
    const char* gB1 = (const char*)(Bw + (long)(n0 + 64 + srow) * K) + sseg;
    const int lofs = wave * 1024;

    f32x4 acc[4][4] = {};

    // prologue: stage tile 0 into buffer 0 (4 loads in flight)
    gload16(gA0, (char*)As[0] + lofs);
    gload16(gA1, (char*)As[0] + 4096 + lofs);
    gload16(gB0, (char*)Bs[0] + lofs);
    gload16(gB1, (char*)Bs[0] + 4096 + lofs);

    int cur = 0;
    for (int kt = 0; kt < nk; kt++) {
        if (kt + 1 < nk) {               // stage NEXT tile; stays in flight past barrier
            gload16(gA0 + (kt + 1) * 64, (char*)As[cur ^ 1] + lofs);
            gload16(gA1 + (kt + 1) * 64, (char*)As[cur ^ 1] + 4096 + lofs);
            gload16(gB0 + (kt + 1) * 64, (char*)Bs[cur ^ 1] + lofs);
            gload16(gB1 + (kt + 1) * 64, (char*)Bs[cur ^ 1] + 4096 + lofs);
            asm volatile("s_waitcnt vmcnt(4)" ::: "memory");   // oldest 4 (= buf[cur]) done
        } else {
            asm volatile("s_waitcnt vmcnt(0)" ::: "memory");   // last tile: drain
        }
        __builtin_amdgcn_sched_barrier(0);
        __builtin_amdgcn_s_barrier();      // all waves' buf[cur] stage-writes visible
        __builtin_amdgcn_sched_barrier(0);
        bf16x8 af[4], bfr[4];
        #pragma unroll
        for (int mi = 0; mi < 4; mi++)
            af[mi] = *(const bf16x8*)((const char*)As[cur] +
                        (wm + mi * 16 + (lane & 15)) * 64 + ((lane >> 4) << 4));
        #pragma unroll
        for (int ni = 0; ni < 4; ni++)
            bfr[ni] = *(const bf16x8*)((const char*)Bs[cur] +
                        (wn + ni * 16 + (lane & 15)) * 64 + ((lane >> 4) << 4));
        #pragma unroll
        for (int mi = 0; mi < 4; mi++)
            #pragma unroll
            for (int ni = 0; ni < 4; ni++)
                acc[mi][ni] = __builtin_amdgcn_mfma_f32_16x16x32_bf16(
                                  af[mi], bfr[ni], acc[mi][ni], 0, 0, 0);
        // WAR: this wave's ds_reads retired, then block-wide barrier before
        // buf[cur] is overwritten next iteration. No vmcnt drain here.
        asm volatile("s_waitcnt lgkmcnt(0)" ::: "memory");
        __builtin_amdgcn_sched_barrier(0);
        __builtin_amdgcn_s_barrier();
        __builtin_amdgcn_sched_barrier(0);
        cur ^= 1;
    }
    // epilogue: D col = lane&15, row = (lane>>4)*4 + r  (m89-verified layout)
    #pragma unroll
    for (int ni = 0; ni < 4; ni++) {
        const int col = n0 + wn + ni * 16 + (lane & 15);
        const float bv = bias[col];
        #pragma unroll
        for (int mi = 0; mi < 4; mi++) {
            const int row = m0 + wm + mi * 16 + ((lane >> 4) << 2);
            #pragma unroll
            for (int r = 0; r < 4; r++)
                Out[(long)(row + r) * N + col] = f2bf(acc[mi][ni][r] + bv);
        }
    }
}

// ---------------------------------------------------------------------------
// gemmG_f32: G[M][256] = fwe[M][768](fp32) @ WoutT[256][768](bf16)^T, PLUS
// per-row reductions folded into the A staging pass (prep2 eliminated):
//   wmask[row] = (sum|fwe[row]|) != 0,  dvec[row] = fwe[row]·b_out.
// (R13 form, unchanged — frozen to isolate the gemm_bt128 delta.)
// ---------------------------------------------------------------------------
__global__ __launch_bounds__(256)
void gemmG_f32(const float* __restrict__ fwe,           // [51200][768] fp32
               const unsigned short* __restrict__ BwT,  // WoutT [256][768] bf16
               const float* __restrict__ bout,          // [768]
               unsigned short* __restrict__ G,          // [51200][256] bf16
               unsigned char* __restrict__ wmask,       // [51200]
               float* __restrict__ dvec) {              // [51200]
    __shared__ unsigned short As[128 * 32];
    __shared__ unsigned short Bs[128 * 32];
    __shared__ float Bo[G3H];
    const int bid = (int)((blockIdx.x & 7) * (gridDim.x >> 3) + (blockIdx.x >> 3));
    const int m0 = (bid >> 1) << 7;      // 400 M-tiles
    const int n0 = (bid & 1) << 7;       // 2 N-tiles
    const int tid = threadIdx.x;
    const int lane = tid & 63;
    const int wave = tid >> 6;
    const int wm = (wave >> 1) << 6;
    const int wn = (wave & 1) << 6;

    // B staging (gload16): same map as gemm_bt128
    const int srow = tid >> 2;
    const int sseg = (tid & 3) << 4;
    const char* gB0 = (const char*)(BwT + (long)(n0 + srow) * NE) + sseg;
    const char* gB1 = (const char*)(BwT + (long)(n0 + 64 + srow) * NE) + sseg;
    char* lB0 = (char*)Bs + wave * 1024;
    char* lB1 = (char*)Bs + 4096 + wave * 1024;

    // A reg-staging: thread -> (row = tid>>1, 16-wide k-half = tid&1)
    const int arow = tid >> 1;
    const int akh = tid & 1;
    const float* aptr = fwe + (long)(m0 + arow) * NE + akh * 16;
    char* la = (char*)As + arow * 64 + akh * 32;

    for (int i = tid; i < G3H; i += 256) Bo[i] = bout[i];

    float4 fa0 = *(const float4*)(aptr);
    float4 fa1 = *(const float4*)(aptr + 4);
    float4 fa2 = *(const float4*)(aptr + 8);
    float4 fa3 = *(const float4*)(aptr + 12);

    f32x4 acc[4][4] = {};
    float asum = 0.0f, vdot = 0.0f;

    __syncthreads();                     // Bo visible

    for (int kt = 0; kt < 24; kt++) {    // K = 768
        __syncthreads();                 // previous tile's LDS reads complete
        gload16(gB0 + kt * 64, lB0);
        gload16(gB1 + kt * 64, lB1);
        // convert + write A slice, fold reductions (fp32, pre-conversion)
        const float* bo = Bo + kt * 32 + akh * 16;
        const float4 b0 = *(const float4*)(bo);
        const float4 b1 = *(const float4*)(bo + 4);
        const float4 b2 = *(const float4*)(bo + 8);
        const float4 b3 = *(const float4*)(bo + 12);
        asum += fabsf(fa0.x) + fabsf(fa0.y) + fabsf(fa0.z) + fabsf(fa0.w)
              + fabsf(fa1.x) + fabsf(fa1.y) + fabsf(fa1.z) + fabsf(fa1.w)
              + fabsf(fa2.x) + fabsf(fa2.y) + fabsf(fa2.z) + fabsf(fa2.w)
              + fabsf(fa3.x) + fabsf(fa3.y) + fabsf(fa3.z) + fabsf(fa3.w);
        vdot += fa0.x * b0.x + fa0.y * b0.y + fa0.z * b0.z + fa0.w * b0.w
              + fa1.x * b1.x + fa1.y * b1.y + fa1.z * b1.z + fa1.w * b1.w
              + fa2.x * b2.x + fa2.y * b2.y + fa2.z * b2.z + fa2.w * b2.w
              + fa3.x * b3.x + fa3.y * b3.y + fa3.z * b3.z + fa3.w * b3.w;
        bf16x8 v0, v1;
        v0[0] = (short)f2bf(fa0.x); v0[1] = (short)f2bf(fa0.y);
        v0[2] = (short)f2bf(fa0.z); v0[3] = (short)f2bf(fa0.w);
        v0[4] = (short)f2bf(fa1.x); v0[5] = (short)f2bf(fa1.y);
        v0[6] = (short)f2bf(fa1.z); v0[7] = (short)f2bf(fa1.w);
        v1[0] = (short)f2bf(fa2.x); v1[1] = (short)f2bf(fa2.y);
        v1[2] = (short)f2bf(fa2.z); v1[3] = (short)f2bf(fa2.w);
        v1[4] = (short)f2bf(fa3.x); v1[5] = (short)f2bf(fa3.y);
        v1[6] = (short)f2bf(fa3.z); v1[7] = (short)f2bf(fa3.w);
        *(bf16x8*)la = v0;
        *(bf16x8*)(la + 16) = v1;
        asm volatile("s_waitcnt vmcnt(0)" ::: "memory");   // B landed
        __syncthreads();                 // all stages visible (incl. ds_writes)
        if (kt + 1 < 24) {               // A prefetch hides under MFMA phase
            const float* ap = aptr + (kt + 1) * 32;
            fa0 = *(const float4*)(ap);
            fa1 = *(const float4*)(ap + 4);
            fa2 = *(const float4*)(ap + 8);
            fa3 = *(const float4*)(ap + 12);
        }
        bf16x8 af[4], bfr[4];
        #pragma unroll
        for (int mi = 0; mi < 4; mi++)
            af[mi] = *(const bf16x8*)((const char*)As +
                        (wm + mi * 16 + (lane & 15)) * 64 + ((lane >> 4) << 4));
        #pragma unroll
        for (int ni = 0; ni < 4; ni++)
            bfr[ni] = *(const bf16x8*)((const char*)Bs +
                        (wn + ni * 16 + (lane & 15)) * 64 + ((lane >> 4) << 4));
        #pragma unroll
        for (int mi = 0; mi < 4; mi++)
            #pragma unroll
            for (int ni = 0; ni < 4; ni++)
                acc[mi][ni] = __builtin_amdgcn_mfma_f32_16x16x32_bf16(
                                  af[mi], bfr[ni], acc[mi][ni], 0, 0, 0);
    }
    // reductions: combine the row's two k-half threads (t, t^1 in same wave)
    asum += __shfl_xor(asum, 1);
    vdot += __shfl_xor(vdot, 1);
    if (akh == 0) {
        wmask[m0 + arow] = (asum != 0.0f) ? 1 : 0;
        dvec[m0 + arow] = vdot;
    }
    // G epilogue (no bias)
    #pragma unroll
    for (int ni = 0; ni < 4; ni++) {
        const int col = n0 + wn + ni * 16 + (lane & 15);
        #pragma unroll
        for (int mi = 0; mi < 4; mi++) {
            const int row = m0 + wm + mi * 16 + ((lane >> 4) << 2);
            #pragma unroll
            for (int r = 0; r < 4; r++)
                G[(long)(row + r) * NH + col] = f2bf(acc[mi][ni][r]);
        }
    }
}

// ---------------------------------------------------------------------------
// gru_scan: 256 blocks (1 batch each), 512 threads (8 waves, 2/SIMD).
// Pure-VALU int8 GEMV via v_dot4_i32_i8 (R7/R8 structure, unchanged).
// ---------------------------------------------------------------------------
__global__ __launch_bounds__(512, 2)
__attribute__((amdgpu_waves_per_eu(2, 2)))
void gru_scan(const unsigned short* __restrict__ xg,   // [51200][768] bf16 (incl biasC)
              const float* __restrict__ Whh,            // [768][256] fp32
              const float* __restrict__ bhh,            // [768]
              const int* __restrict__ lengths,          // [256]
              unsigned short* __restrict__ hout) {      // [51200][256] bf16 (masked)
    __shared__ __align__(16) unsigned char h8[2][256];  // int8 h double buffer
    const int tid = threadIdx.x;
    const int lane = tid & 63;
    const int wave = tid >> 6;               // 0..7
    const int b = blockIdx.x;
    const int col = wave * 32 + (lane & 31); // this thread's h-col
    const int kh = lane >> 5;                // K-half 0/1

    int W[3][32];
    #pragma unroll
    for (int g = 0; g < 3; g++) {
        const float* wr = Whh + (long)(g * 256 + col) * NH + kh * 128;
        #pragma unroll
        for (int d = 0; d < 32; d++) {
            const float4 f = *(const float4*)(wr + d * 4);
            unsigned pack = 0;
            #pragma unroll
            for (int j = 0; j < 4; j++) {
                const float fv = j == 0 ? f.x : j == 1 ? f.y : j == 2 ? f.z : f.w;
                int wq = (int)rintf(fv * 400.0f);
                wq = wq > 127 ? 127 : (wq < -127 ? -127 : wq);
                pack |= ((unsigned)(wq & 0xff)) << (8 * j);
            }
            W[g][d] = (int)pack;
        }
    }
    const float bhn = bhh[512 + col];        // n-gate b_hh (r,z folded into xg)
    const int len = lengths[b];
    if (tid < 128) ((unsigned*)h8)[tid] = 0u;   // zero both h buffers (512 B)

    const unsigned short* xrow = xg + (long)b * NT * G3H;
    unsigned short xv0 = xrow[col], xv1 = xrow[256 + col], xv2 = xrow[512 + col];
    float hp = 0.0f;
    const float ISC = 1.0f / (400.0f * 127.0f);
    const bool wlo = (lane < 32);

    asm volatile("s_waitcnt lgkmcnt(0)" ::: "memory");
    __builtin_amdgcn_sched_barrier(0);
    __builtin_amdgcn_s_barrier();
    __builtin_amdgcn_sched_barrier(0);

    for (int t = 0; t < NT; t++) {
        const unsigned char* hb = h8[(t + 1) & 1] + kh * 128;
        int p0a = 0, p0b = 0, p1a = 0, p1b = 0, p2a = 0, p2b = 0;
        #pragma unroll
        for (int r = 0; r < 8; r++) {
            const i32x4 hv = *(const i32x4*)(hb + r * 16);
            p0a = SDOT4(hv[0], W[0][r * 4 + 0], p0a);
            p1a = SDOT4(hv[0], W[1][r * 4 + 0], p1a);
            p2a = SDOT4(hv[0], W[2][r * 4 + 0], p2a);
            p0b = SDOT4(hv[1], W[0][r * 4 + 1], p0b);
            p1b = SDOT4(hv[1], W[1][r * 4 + 1], p1b);
            p2b = SDOT4(hv[1], W[2][r * 4 + 1], p2b);
            p0a = SDOT4(hv[2], W[0][r * 4 + 2], p0a);
            p1a = SDOT4(hv[2], W[1][r * 4 + 2], p1a);
            p2a = SDOT4(hv[2], W[2][r * 4 + 2], p2a);
            p0b = SDOT4(hv[3], W[0][r * 4 + 3], p0b);
            p1b = SDOT4(hv[3], W[1][r * 4 + 3], p1b);
            p2b = SDOT4(hv[3], W[2][r * 4 + 3], p2b);
        }
        int p0 = p0a + p0b, p1 = p1a + p1b, p2 = p2a + p2b;
        p0 += __shfl_xor(p0, 32);            // combine K-halves
        p1 += __shfl_xor(p1, 32);
        p2 += __shfl_xor(p2, 32);
        const float r = sigm(bf2f(xv0) + (float)p0 * ISC);
        const float z = sigm(bf2f(xv1) + (float)p1 * ISC);
        const float n = tanh_fast(bf2f(xv2) + r * ((float)p2 * ISC + bhn));
        hp = (1.0f - z) * n + z * hp;
        if (wlo) {
            h8[t & 1][col] = (unsigned char)((int)rintf(hp * 127.0f) & 0xff);
            hout[((long)b * NT + t) * NH + col] = (t < len) ? f2bf(hp) : (unsigned short)0;
        }
        if (t + 1 < NT) {
            const unsigned short* xn = xrow + (long)(t + 1) * G3H;
            xv0 = xn[col]; xv1 = xn[256 + col]; xv2 = xn[512 + col];
        }
        asm volatile("s_waitcnt lgkmcnt(0)" ::: "memory");
        __builtin_amdgcn_sched_barrier(0);
        __builtin_amdgcn_s_barrier();
        __builtin_amdgcn_sched_barrier(0);
    }
}

// ---------------------------------------------------------------------------
// logits_dur: wave per (b,t) row; only |w-fix|<=8 dots computed; dur fused.
// (R11 form, unchanged.)
// ---------------------------------------------------------------------------
__global__ __launch_bounds__(256)
void logits_dur(const unsigned short* __restrict__ Hrow,   // hout [51200][256]
                const unsigned short* __restrict__ G,      // [51200][256]
                const int* __restrict__ fix_seq,           // [51200]
                const unsigned char* __restrict__ wmask,   // [51200]
                const float* __restrict__ dvec,            // [51200]
                const float* __restrict__ Wdur, const float* __restrict__ bdur,
                float* __restrict__ out) {
    __shared__ float dots[4][20];
    const int wv = threadIdx.x >> 6;
    const int gwave = (int)blockIdx.x * 4 + wv;            // 0..51199 = b*200+t
    const int lane = threadIdx.x & 63;
    const int l16 = lane & 15;
    const int grp = lane >> 4;                              // 0..3
    const int b = gwave / NT;

    const unsigned short* hp = Hrow + (long)gwave * NH + l16 * 16;
    const bf16x8 h0 = *(const bf16x8*)hp;
    const bf16x8 h1 = *(const bf16x8*)(hp + 8);
    float hf[16];
    #pragma unroll
    for (int j = 0; j < 8; j++) { hf[j] = bf2f((unsigned short)h0[j]);
                                  hf[8 + j] = bf2f((unsigned short)h1[j]); }

    const int fix = fix_seq[gwave];
    const int wbase = fix - 8;

    if (fix != 0) {
        #pragma unroll
        for (int it = 0; it < 5; it++) {
            const int wi = it * 4 + grp;                    // 0..19 (17..19 unused)
            int w = wbase + wi;
            w = w < 0 ? 0 : (w > NW - 1 ? NW - 1 : w);      // clamp for safe load
            const unsigned short* gp = G + ((long)b * NW + w) * NH + l16 * 16;
            const bf16x8 g0 = *(const bf16x8*)gp;
            const bf16x8 g1 = *(const bf16x8*)(gp + 8);
            float p = 0.0f;
            #pragma unroll
            for (int j = 0; j < 8; j++) {
                p += hf[j] * bf2f((unsigned short)g0[j]);
                p += hf[8 + j] * bf2f((unsigned short)g1[j]);
            }
            p += __shfl_xor(p, 1); p += __shfl_xor(p, 2);
            p += __shfl_xor(p, 4); p += __shfl_xor(p, 8);
            if (l16 == 0 && wi < 17) dots[wv][wi] = p;
        }
    }
    float pd = 0.0f;
    #pragma unroll
    for (int j = 0; j < 16; j++) pd += hf[j] * Wdur[l16 * 16 + j];
    pd += __shfl_xor(pd, 1); pd += __shfl_xor(pd, 2);
    pd += __shfl_xor(pd, 4); pd += __shfl_xor(pd, 8);
    if (lane == 0) out[(long)NB * NT * NW + gwave] = pd + bdur[0];

    __syncthreads();

    if (lane < 50) {
        float4 o;
        #pragma unroll
        for (int c = 0; c < 4; c++) {
            const int w = lane * 4 + c;
            const int wi = w - wbase;
            const int wic = wi < 0 ? 0 : (wi > 16 ? 16 : wi);
            const bool ok = (fix != 0) && ((unsigned)wi < 17u) && (wmask[b * NW + w] != 0);
            const float val = dots[wv][wic] + dvec[b * NW + w];
            ((float*)&o)[c] = ok ? val : -1e9f;
        }
        *(float4*)(out + (long)gwave * NW + lane * 4) = o;
    }
}

// ---------------------------------------------------------------------------
extern "C" void kernel_launch(void* const* d_in, const int* in_sizes, int n_in,
                              void* d_out, int out_size, void* d_ws, size_t ws_size,
                              hipStream_t stream) {
    (void)in_sizes; (void)n_in; (void)out_size; (void)ws_size;
    const float* inputs  = (const float*)d_in[0];
    const int*   fix_seq = (const int*)d_in[1];
    const float* fwe     = (const float*)d_in[2];
    const int*   lengths = (const int*)d_in[3];
    const float* emb     = (const float*)d_in[5];
    const float* Wih     = (const float*)d_in[6];
    const float* bih     = (const float*)d_in[7];
    const float* Whh     = (const float*)d_in[8];
    const float* bhh     = (const float*)d_in[9];
    const float* Wout    = (const float*)d_in[10];
    const float* bout    = (const float*)d_in[11];
    const float* Wdur    = (const float*)d_in[12];
    const float* bdur    = (const float*)d_in[13];
    float* out = (float*)d_out;

    char* ws = (char*)d_ws;
    // region layout (bytes, all 256-aligned):
    //   R0 [0, 81,920,000)            A_bf16 [51200][800]  -> G [51200][256] after gemm1
    //   R1 [81,920,000, +78,643,200)  xg_bf16 [51200][768]
    //   R2 [160,563,200, +26,214,400) hout_bf16 [51200][256]
    //   [186,777,600, +1,228,800)     W_ih bf16
    //   [188,006,400, +393,216)       W_outT bf16 [256][768]
    //   [188,399,616, +51,200)        word_mask u8
    //   [188,450,816, +3,072)         biasC f32 [768]
    //   [188,453,888, +204,800)       dvec f32 [51200]
    unsigned short* Abf     = (unsigned short*)(ws);
    unsigned short* xgbf    = (unsigned short*)(ws + 81920000);
    unsigned short* hout    = (unsigned short*)(ws + 160563200);
    unsigned short* Wihbf   = (unsigned short*)(ws + 186777600);
    unsigned short* WoutTbf = (unsigned short*)(ws + 188006400);
    unsigned char*  wmask   = (unsigned char*)(ws + 188399616);
    float*          biasC   = (float*)(ws + 188450816);
    float*          dvec    = (float*)(ws + 188453888);
    unsigned short* Gbf     = Abf;    // R0: A dead after gemm1

    prep1<<<2048, 256, 0, stream>>>(inputs, fix_seq, emb, Wih, Wout, bih, bhh,
                                    Abf, Wihbf, WoutTbf, biasC);
    gemm_bt128<<<400 * 6, 256, 0, stream>>>(Abf, Wihbf, biasC, xgbf, MROWS, G3H, KIN);
    gemmG_f32<<<800, 256, 0, stream>>>(fwe, WoutTbf, bout, Gbf, wmask, dvec);
    gru_scan<<<256, 512, 0, stream>>>(xgbf, Whh, bhh, lengths, hout);
    logits_dur<<<12800, 256, 0, stream>>>(hout, Gbf, fix_seq, wmask, dvec, Wdur, bdur, out);
}

// Round 15
// 463.443 us; speedup vs baseline: 1.1196x; 1.0787x over previous
//
#include <hip/hip_runtime.h>
#include <hip/hip_bf16.h>

typedef __attribute__((ext_vector_type(8))) short bf16x8;   // 8 bf16 in 4 VGPRs
typedef __attribute__((ext_vector_type(4))) float f32x4;    // MFMA accumulator
typedef __attribute__((ext_vector_type(4))) int   i32x4;

#define NB 256
#define NT 200
#define NW 200
#define NE 768
#define NH 256
#define NEMB 32
#define KIN 800           // E + EMB
#define G3H 768           // 3*H
#define MROWS 51200       // B*T

__device__ __forceinline__ float bf2f(unsigned short h) {
    return __uint_as_float(((unsigned)h) << 16);
}
__device__ __forceinline__ unsigned short f2bf(float f) {
    unsigned u = __float_as_uint(f);
    u += 0x7fff + ((u >> 16) & 1);   // RNE
    return (unsigned short)(u >> 16);
}
__device__ __forceinline__ float sigm(float x) { return 1.0f / (1.0f + __expf(-x)); }
__device__ __forceinline__ float tanh_fast(float x) {
    float e = __expf(2.0f * x);
    return 1.0f - 2.0f / (e + 1.0f);
}

#if __has_builtin(__builtin_amdgcn_sdot4)
__device__ __forceinline__ int SDOT4(int a, int b, int c) {
    return __builtin_amdgcn_sdot4(a, b, c, false);
}
#else
__device__ __forceinline__ int SDOT4(int a, int b, int c) {   // exact fallback
    #pragma unroll
    for (int j = 0; j < 4; j++)
        c += (int)(signed char)(a >> (8 * j)) * (int)(signed char)(b >> (8 * j));
    return c;
}
#endif

// async global->LDS, 16 B/lane. LDS dest: wave-uniform base + lane*16.
__device__ __forceinline__ void gload16(const void* g, void* l) {
    __builtin_amdgcn_global_load_lds((const __attribute__((address_space(1))) unsigned int*)g,
                                     (__attribute__((address_space(3))) unsigned int*)l,
                                     16, 0, 0);
}

// ---------------------------------------------------------------------------
// prep1: A_bf16[51200][800] = [bf16(inputs) | bf16(emb_table[fix])],
//        W_ih -> bf16 [768][800], W_out -> bf16 TRANSPOSED [256][768],
//        biasC[768] = b_ih + (row<512 ? b_hh : 0)
// ---------------------------------------------------------------------------
__global__ void prep1(const float* __restrict__ inputs, const int* __restrict__ fix_seq,
                      const float* __restrict__ emb, const float* __restrict__ Wih,
                      const float* __restrict__ Wout, const float* __restrict__ bih,
                      const float* __restrict__ bhh,
                      unsigned short* __restrict__ Abf, unsigned short* __restrict__ Wihbf,
                      unsigned short* __restrict__ WoutTbf, float* __restrict__ biasC) {
    const long gid0 = (long)blockIdx.x * blockDim.x + threadIdx.x;
    if (gid0 < G3H) biasC[gid0] = bih[gid0] + (gid0 < 512 ? bhh[gid0] : 0.0f);
    const long NA = (long)MROWS * 100;   // 8 cols per unit
    const long NWU = 768L * 100;
    const long NOU = 256L * 96;          // WoutT: 256 rows x 96 8-col chunks
    const long total = NA + NWU + NOU;
    for (long u = gid0; u < total; u += (long)gridDim.x * blockDim.x) {
        bf16x8 v;
        unsigned short* dst;
        if (u < NA) {
            long row = u / 100;
            int c8 = (int)(u % 100) * 8;
            const float* s;
            if (c8 < NE) {
                s = inputs + row * NE + c8;
            } else {
                int fx = fix_seq[row];
                s = emb + (long)fx * NEMB + (c8 - NE);
            }
            #pragma unroll
            for (int j = 0; j < 8; j++) v[j] = (short)f2bf(s[j]);
            dst = Abf + row * KIN + c8;
        } else if (u < NA + NWU) {
            long u2 = u - NA;
            long row = u2 / 100;
            int c8 = (int)(u2 % 100) * 8;
            const float* s = Wih + row * KIN + c8;
            #pragma unroll
            for (int j = 0; j < 8; j++) v[j] = (short)f2bf(s[j]);
            dst = Wihbf + row * KIN + c8;
        } else {
            long u3 = u - NA - NWU;
            long row = u3 / 96;          // h index 0..255
            int c8 = (int)(u3 % 96) * 8; // e chunk
            #pragma unroll
            for (int j = 0; j < 8; j++)
                v[j] = (short)f2bf(Wout[(long)(c8 + j) * NH + row]);   // transpose gather
            dst = WoutTbf + row * NE + c8;
        }
        *(bf16x8*)dst = v;
    }
}

// ---------------------------------------------------------------------------
// gemm_bt128: Out[M][N] (bf16) = A[M][K](bf16) * Bw[N][K](bf16)^T + bias
// BM=BN=128, BK=32, 256 threads. T4 counted-vmcnt pipeline (R14 form).
// ---------------------------------------------------------------------------
__global__ __launch_bounds__(256)
void gemm_bt128(const unsigned short* __restrict__ A,
                const unsigned short* __restrict__ Bw,
                const float* __restrict__ bias,
                unsigned short* __restrict__ Out,
                int M, int N, int K) {
    __shared__ unsigned short As[2][128 * 32];
    __shared__ unsigned short Bs[2][128 * 32];
    const int bid = (int)((blockIdx.x & 7) * (gridDim.x >> 3) + (blockIdx.x >> 3));
    const int nblk = N >> 7;
    const int m0 = (bid / nblk) << 7;
    const int n0 = (bid % nblk) << 7;
    const int tid = threadIdx.x;
    const int lane = tid & 63;
    const int wave = tid >> 6;
    const int wm = (wave >> 1) << 6;
    const int wn = (wave & 1) << 6;
    const int nk = K >> 5;

    const int srow = tid >> 2;
    const int sseg = (tid & 3) << 4;
    const char* gA0 = (const char*)(A + (long)(m0 + srow) * K) + sseg;        // rows 0-63
    const char* gA1 = (const char*)(A + (long)(m0 + 64 + srow) * K) + sseg;   // rows 64-127
    const char* gB0 = (const char*)(Bw + (long)(n0 + srow) * K) + sseg;
    const char* gB1 = (const char*)(Bw + (long)(n0 + 64 + srow) * K) + sseg;
    const int lofs = wave * 1024;

    f32x4 acc[4][4] = {};

    // prologue: stage tile 0 into buffer 0 (4 loads in flight)
    gload16(gA0, (char*)As[0] + lofs);
    gload16(gA1, (char*)As[0] + 4096 + lofs);
    gload16(gB0, (char*)Bs[0] + lofs);
    gload16(gB1, (char*)Bs[0] + 4096 + lofs);

    int cur = 0;
    for (int kt = 0; kt < nk; kt++) {
        if (kt + 1 < nk) {               // stage NEXT tile; stays in flight past barrier
            gload16(gA0 + (kt + 1) * 64, (char*)As[cur ^ 1] + lofs);
            gload16(gA1 + (kt + 1) * 64, (char*)As[cur ^ 1] + 4096 + lofs);
            gload16(gB0 + (kt + 1) * 64, (char*)Bs[cur ^ 1] + lofs);
            gload16(gB1 + (kt + 1) * 64, (char*)Bs[cur ^ 1] + 4096 + lofs);
            asm volatile("s_waitcnt vmcnt(4)" ::: "memory");   // oldest 4 (= buf[cur]) done
        } else {
            asm volatile("s_waitcnt vmcnt(0)" ::: "memory");   // last tile: drain
        }
        __builtin_amdgcn_sched_barrier(0);
        __builtin_amdgcn_s_barrier();      // all waves' buf[cur] stage-writes visible
        __builtin_amdgcn_sched_barrier(0);
        bf16x8 af[4], bfr[4];
        #pragma unroll
        for (int mi = 0; mi < 4; mi++)
            af[mi] = *(const bf16x8*)((const char*)As[cur] +
                        (wm + mi * 16 + (lane & 15)) * 64 + ((lane >> 4) << 4));
        #pragma unroll
        for (int ni = 0; ni < 4; ni++)
            bfr[ni] = *(const bf16x8*)((const char*)Bs[cur] +
                        (wn + ni * 16 + (lane & 15)) * 64 + ((lane >> 4) << 4));
        #pragma unroll
        for (int mi = 0; mi < 4; mi++)
            #pragma unroll
            for (int ni = 0; ni < 4; ni++)
                acc[mi][ni] = __builtin_amdgcn_mfma_f32_16x16x32_bf16(
                                  af[mi], bfr[ni], acc[mi][ni], 0, 0, 0);
        // WAR: this wave's ds_reads retired, then block-wide barrier before
        // buf[cur] is overwritten next iteration. No vmcnt drain here.
        asm volatile("s_waitcnt lgkmcnt(0)" ::: "memory");
        __builtin_amdgcn_sched_barrier(0);
        __builtin_amdgcn_s_barrier();
        __builtin_amdgcn_sched_barrier(0);
        cur ^= 1;
    }
    // epilogue: D col = lane&15, row = (lane>>4)*4 + r  (m89-verified layout)
    #pragma unroll
    for (int ni = 0; ni < 4; ni++) {
        const int col = n0 + wn + ni * 16 + (lane & 15);
        const float bv = bias[col];
        #pragma unroll
        for (int mi = 0; mi < 4; mi++) {
            const int row = m0 + wm + mi * 16 + ((lane >> 4) << 2);
            #pragma unroll
            for (int r = 0; r < 4; r++)
                Out[(long)(row + r) * N + col] = f2bf(acc[mi][ni][r] + bv);
        }
    }
}

// ---------------------------------------------------------------------------
// gemmG_f32: G[M][256] = fwe[M][768](fp32) @ WoutT[256][768](bf16)^T.
// BN = 256 (FULL N per block) -> fwe read exactly ONCE (R13/R14 read it
// twice via 2 N-tile blocks; at 157 MB fp32 that duplication was the
// kernel's memory bound). 400 blocks x 512 threads (8 waves = 2Mx4N of
// 64x64). Per-row reductions (wmask, dvec = fwe_row . b_out) folded into
// the A staging pass, now with a single writer per row.
// ---------------------------------------------------------------------------
__global__ __launch_bounds__(512)
void gemmG_f32(const float* __restrict__ fwe,           // [51200][768] fp32
               const unsigned short* __restrict__ BwT,  // WoutT [256][768] bf16
               const float* __restrict__ bout,          // [768]
               unsigned short* __restrict__ G,          // [51200][256] bf16
               unsigned char* __restrict__ wmask,       // [51200]
               float* __restrict__ dvec) {              // [51200]
    __shared__ unsigned short As[128 * 32];   //  8 KB
    __shared__ unsigned short Bs[256 * 32];   // 16 KB
    __shared__ float Bo[G3H];                 //  3 KB
    const int m0 = (int)blockIdx.x << 7;
    const int tid = threadIdx.x;
    const int lane = tid & 63;
    const int wave = tid >> 6;
    const int wm = (wave >> 2) << 6;     // 0 / 64
    const int wn = (wave & 3) << 6;      // 0 / 64 / 128 / 192

    // A reg-staging: row = tid>>2 (0..127), k-quarter kq = tid&3 (8 floats)
    const int arow = tid >> 2;
    const int akq = tid & 3;
    const float* aptr = fwe + (long)(m0 + arow) * NE + akq * 8;
    char* la = (char*)As + arow * 64 + akq * 16;

    // B staging (gload16, 2 rounds): thread -> row tid>>2 (+128), seg tid&3
    const int sseg = (tid & 3) << 4;
    const char* gBa = (const char*)(BwT + (long)arow * NE) + sseg;          // rows 0-127
    const char* gBb = (const char*)(BwT + (long)(128 + arow) * NE) + sseg;  // rows 128-255
    char* lBa = (char*)Bs + wave * 1024;
    char* lBb = (char*)Bs + 8192 + wave * 1024;

    for (int i = tid; i < G3H; i += 512) Bo[i] = bout[i];

    float4 fa0 = *(const float4*)(aptr);
    float4 fa1 = *(const float4*)(aptr + 4);

    f32x4 acc[4][4] = {};
    float asum = 0.0f, vdot = 0.0f;

    __syncthreads();                     // Bo visible

    for (int kt = 0; kt < 24; kt++) {    // K = 768
        __syncthreads();                 // previous tile's LDS reads complete
        gload16(gBa + kt * 64, lBa);
        gload16(gBb + kt * 64, lBb);
        // fold reductions (fp32, pre-conversion), convert + write A slice
        const float* bo = Bo + kt * 32 + akq * 8;
        const float4 b0 = *(const float4*)(bo);
        const float4 b1 = *(const float4*)(bo + 4);
        asum += fabsf(fa0.x) + fabsf(fa0.y) + fabsf(fa0.z) + fabsf(fa0.w)
              + fabsf(fa1.x) + fabsf(fa1.y) + fabsf(fa1.z) + fabsf(fa1.w);
        vdot += fa0.x * b0.x + fa0.y * b0.y + fa0.z * b0.z + fa0.w * b0.w
              + fa1.x * b1.x + fa1.y * b1.y + fa1.z * b1.z + fa1.w * b1.w;
        bf16x8 v;
        v[0] = (short)f2bf(fa0.x); v[1] = (short)f2bf(fa0.y);
        v[2] = (short)f2bf(fa0.z); v[3] = (short)f2bf(fa0.w);
        v[4] = (short)f2bf(fa1.x); v[5] = (short)f2bf(fa1.y);
        v[6] = (short)f2bf(fa1.z); v[7] = (short)f2bf(fa1.w);
        *(bf16x8*)la = v;
        asm volatile("s_waitcnt vmcnt(0)" ::: "memory");   // B landed
        __syncthreads();                 // all stages visible (incl. ds_writes)
        if (kt + 1 < 24) {               // A prefetch hides under MFMA phase
            const float* ap = aptr + (kt + 1) * 32;
            fa0 = *(const float4*)(ap);
            fa1 = *(const float4*)(ap + 4);
        }
        bf16x8 af[4], bfr[4];
        #pragma unroll
        for (int mi = 0; mi < 4; mi++)
            af[mi] = *(const bf16x8*)((const char*)As +
                        (wm + mi * 16 + (lane & 15)) * 64 + ((lane >> 4) << 4));
        #pragma unroll
        for (int ni = 0; ni < 4; ni++)
            bfr[ni] = *(const bf16x8*)((const char*)Bs +
                        (wn + ni * 16 + (lane & 15)) * 64 + ((lane >> 4) << 4));
        #pragma unroll
        for (int mi = 0; mi < 4; mi++)
            #pragma unroll
            for (int ni = 0; ni < 4; ni++)
                acc[mi][ni] = __builtin_amdgcn_mfma_f32_16x16x32_bf16(
                                  af[mi], bfr[ni], acc[mi][ni], 0, 0, 0);
    }
    // reductions: combine the row's 4 k-quarter threads (consecutive lanes)
    asum += __shfl_xor(asum, 1);  asum += __shfl_xor(asum, 2);
    vdot += __shfl_xor(vdot, 1);  vdot += __shfl_xor(vdot, 2);
    if (akq == 0) {
        wmask[m0 + arow] = (asum != 0.0f) ? 1 : 0;
        dvec[m0 + arow] = vdot;
    }
    // G epilogue (no bias)
    #pragma unroll
    for (int ni = 0; ni < 4; ni++) {
        const int col = wn + ni * 16 + (lane & 15);
        #pragma unroll
        for (int mi = 0; mi < 4; mi++) {
            const int row = m0 + wm + mi * 16 + ((lane >> 4) << 2);
            #pragma unroll
            for (int r = 0; r < 4; r++)
                G[(long)(row + r) * NH + col] = f2bf(acc[mi][ni][r]);
        }
    }
}

// ---------------------------------------------------------------------------
// gru_scan: 256 blocks (1 batch each), 512 threads (8 waves, 2/SIMD).
// Pure-VALU int8 GEMV via v_dot4_i32_i8 (R7/R8 structure, unchanged).
// ---------------------------------------------------------------------------
__global__ __launch_bounds__(512, 2)
__attribute__((amdgpu_waves_per_eu(2, 2)))
void gru_scan(const unsigned short* __restrict__ xg,   // [51200][768] bf16 (incl biasC)
              const float* __restrict__ Whh,            // [768][256] fp32
              const float* __restrict__ bhh,            // [768]
              const int* __restrict__ lengths,          // [256]
              unsigned short* __restrict__ hout) {      // [51200][256] bf16 (masked)
    __shared__ __align__(16) unsigned char h8[2][256];  // int8 h double buffer
    const int tid = threadIdx.x;
    const int lane = tid & 63;
    const int wave = tid >> 6;               // 0..7
    const int b = blockIdx.x;
    const int col = wave * 32 + (lane & 31); // this thread's h-col
    const int kh = lane >> 5;                // K-half 0/1

    int W[3][32];
    #pragma unroll
    for (int g = 0; g < 3; g++) {
        const float* wr = Whh + (long)(g * 256 + col) * NH + kh * 128;
        #pragma unroll
        for (int d = 0; d < 32; d++) {
            const float4 f = *(const float4*)(wr + d * 4);
            unsigned pack = 0;
            #pragma unroll
            for (int j = 0; j < 4; j++) {
                const float fv = j == 0 ? f.x : j == 1 ? f.y : j == 2 ? f.z : f.w;
                int wq = (int)rintf(fv * 400.0f);
                wq = wq > 127 ? 127 : (wq < -127 ? -127 : wq);
                pack |= ((unsigned)(wq & 0xff)) << (8 * j);
            }
            W[g][d] = (int)pack;
        }
    }
    const float bhn = bhh[512 + col];        // n-gate b_hh (r,z folded into xg)
    const int len = lengths[b];
    if (tid < 128) ((unsigned*)h8)[tid] = 0u;   // zero both h buffers (512 B)

    const unsigned short* xrow = xg + (long)b * NT * G3H;
    unsigned short xv0 = xrow[col], xv1 = xrow[256 + col], xv2 = xrow[512 + col];
    float hp = 0.0f;
    const float ISC = 1.0f / (400.0f * 127.0f);
    const bool wlo = (lane < 32);

    asm volatile("s_waitcnt lgkmcnt(0)" ::: "memory");
    __builtin_amdgcn_sched_barrier(0);
    __builtin_amdgcn_s_barrier();
    __builtin_amdgcn_sched_barrier(0);

    for (int t = 0; t < NT; t++) {
        const unsigned char* hb = h8[(t + 1) & 1] + kh * 128;
        int p0a = 0, p0b = 0, p1a = 0, p1b = 0, p2a = 0, p2b = 0;
        #pragma unroll
        for (int r = 0; r < 8; r++) {
            const i32x4 hv = *(const i32x4*)(hb + r * 16);
            p0a = SDOT4(hv[0], W[0][r * 4 + 0], p0a);
            p1a = SDOT4(hv[0], W[1][r * 4 + 0], p1a);
            p2a = SDOT4(hv[0], W[2][r * 4 + 0], p2a);
            p0b = SDOT4(hv[1], W[0][r * 4 + 1], p0b);
            p1b = SDOT4(hv[1], W[1][r * 4 + 1], p1b);
            p2b = SDOT4(hv[1], W[2][r * 4 + 1], p2b);
            p0a = SDOT4(hv[2], W[0][r * 4 + 2], p0a);
            p1a = SDOT4(hv[2], W[1][r * 4 + 2], p1a);
            p2a = SDOT4(hv[2], W[2][r * 4 + 2], p2a);
            p0b = SDOT4(hv[3], W[0][r * 4 + 3], p0b);
            p1b = SDOT4(hv[3], W[1][r * 4 + 3], p1b);
            p2b = SDOT4(hv[3], W[2][r * 4 + 3], p2b);
        }
        int p0 = p0a + p0b, p1 = p1a + p1b, p2 = p2a + p2b;
        p0 += __shfl_xor(p0, 32);            // combine K-halves
        p1 += __shfl_xor(p1, 32);
        p2 += __shfl_xor(p2, 32);
        const float r = sigm(bf2f(xv0) + (float)p0 * ISC);
        const float z = sigm(bf2f(xv1) + (float)p1 * ISC);
        const float n = tanh_fast(bf2f(xv2) + r * ((float)p2 * ISC + bhn));
        hp = (1.0f - z) * n + z * hp;
        if (wlo) {
            h8[t & 1][col] = (unsigned char)((int)rintf(hp * 127.0f) & 0xff);
            hout[((long)b * NT + t) * NH + col] = (t < len) ? f2bf(hp) : (unsigned short)0;
        }
        if (t + 1 < NT) {
            const unsigned short* xn = xrow + (long)(t + 1) * G3H;
            xv0 = xn[col]; xv1 = xn[256 + col]; xv2 = xn[512 + col];
        }
        asm volatile("s_waitcnt lgkmcnt(0)" ::: "memory");
        __builtin_amdgcn_sched_barrier(0);
        __builtin_amdgcn_s_barrier();
        __builtin_amdgcn_sched_barrier(0);
    }
}

// ---------------------------------------------------------------------------
// logits_dur: wave per (b,t) row; only |w-fix|<=8 dots computed; dur fused.
// (R11 form, unchanged.)
// ---------------------------------------------------------------------------
__global__ __launch_bounds__(256)
void logits_dur(const unsigned short* __restrict__ Hrow,   // hout [51200][256]
                const unsigned short* __restrict__ G,      // [51200][256]
                const int* __restrict__ fix_seq,           // [51200]
                const unsigned char* __restrict__ wmask,   // [51200]
                const float* __restrict__ dvec,            // [51200]
                const float* __restrict__ Wdur, const float* __restrict__ bdur,
                float* __restrict__ out) {
    __shared__ float dots[4][20];
    const int wv = threadIdx.x >> 6;
    const int gwave = (int)blockIdx.x * 4 + wv;            // 0..51199 = b*200+t
    const int lane = threadIdx.x & 63;
    const int l16 = lane & 15;
    const int grp = lane >> 4;                              // 0..3
    const int b = gwave / NT;

    const unsigned short* hp = Hrow + (long)gwave * NH + l16 * 16;
    const bf16x8 h0 = *(const bf16x8*)hp;
    const bf16x8 h1 = *(const bf16x8*)(hp + 8);
    float hf[16];
    #pragma unroll
    for (int j = 0; j < 8; j++) { hf[j] = bf2f((unsigned short)h0[j]);
                                  hf[8 + j] = bf2f((unsigned short)h1[j]); }

    const int fix = fix_seq[gwave];
    const int wbase = fix - 8;

    if (fix != 0) {
        #pragma unroll
        for (int it = 0; it < 5; it++) {
            const int wi = it * 4 + grp;                    // 0..19 (17..19 unused)
            int w = wbase + wi;
            w = w < 0 ? 0 : (w > NW - 1 ? NW - 1 : w);      // clamp for safe load
            const unsigned short* gp = G + ((long)b * NW + w) * NH + l16 * 16;
            const bf16x8 g0 = *(const bf16x8*)gp;
            const bf16x8 g1 = *(const bf16x8*)(gp + 8);
            float p = 0.0f;
            #pragma unroll
            for (int j = 0; j < 8; j++) {
                p += hf[j] * bf2f((unsigned short)g0[j]);
                p += hf[8 + j] * bf2f((unsigned short)g1[j]);
            }
            p += __shfl_xor(p, 1); p += __shfl_xor(p, 2);
            p += __shfl_xor(p, 4); p += __shfl_xor(p, 8);
            if (l16 == 0 && wi < 17) dots[wv][wi] = p;
        }
    }
    float pd = 0.0f;
    #pragma unroll
    for (int j = 0; j < 16; j++) pd += hf[j] * Wdur[l16 * 16 + j];
    pd += __shfl_xor(pd, 1); pd += __shfl_xor(pd, 2);
    pd += __shfl_xor(pd, 4); pd += __shfl_xor(pd, 8);
    if (lane == 0) out[(long)NB * NT * NW + gwave] = pd + bdur[0];

    __syncthreads();

    if (lane < 50) {
        float4 o;
        #pragma unroll
        for (int c = 0; c < 4; c++) {
            const int w = lane * 4 + c;
            const int wi = w - wbase;
            const int wic = wi < 0 ? 0 : (wi > 16 ? 16 : wi);
            const bool ok = (fix != 0) && ((unsigned)wi < 17u) && (wmask[b * NW + w] != 0);
            const float val = dots[wv][wic] + dvec[b * NW + w];
            ((float*)&o)[c] = ok ? val : -1e9f;
        }
        *(float4*)(out + (long)gwave * NW + lane * 4) = o;
    }
}

// ---------------------------------------------------------------------------
extern "C" void kernel_launch(void* const* d_in, const int* in_sizes, int n_in,
                              void* d_out, int out_size, void* d_ws, size_t ws_size,
                              hipStream_t stream) {
    (void)in_sizes; (void)n_in; (void)out_size; (void)ws_size;
    const float* inputs  = (const float*)d_in[0];
    const int*   fix_seq = (const int*)d_in[1];
    const float* fwe     = (const float*)d_in[2];
    const int*   lengths = (const int*)d_in[3];
    const float* emb     = (const float*)d_in[5];
    const float* Wih     = (const float*)d_in[6];
    const float* bih     = (const float*)d_in[7];
    const float* Whh     = (const float*)d_in[8];
    const float* bhh     = (const float*)d_in[9];
    const float* Wout    = (const float*)d_in[10];
    const float* bout    = (const float*)d_in[11];
    const float* Wdur    = (const float*)d_in[12];
    const float* bdur    = (const float*)d_in[13];
    float* out = (float*)d_out;

    char* ws = (char*)d_ws;
    // region layout (bytes, all 256-aligned):
    //   R0 [0, 81,920,000)            A_bf16 [51200][800]  -> G [51200][256] after gemm1
    //   R1 [81,920,000, +78,643,200)  xg_bf16 [51200][768]
    //   R2 [160,563,200, +26,214,400) hout_bf16 [51200][256]
    //   [186,777,600, +1,228,800)     W_ih bf16
    //   [188,006,400, +393,216)       W_outT bf16 [256][768]
    //   [188,399,616, +51,200)        word_mask u8
    //   [188,450,816, +3,072)         biasC f32 [768]
    //   [188,453,888, +204,800)       dvec f32 [51200]
    unsigned short* Abf     = (unsigned short*)(ws);
    unsigned short* xgbf    = (unsigned short*)(ws + 81920000);
    unsigned short* hout    = (unsigned short*)(ws + 160563200);
    unsigned short* Wihbf   = (unsigned short*)(ws + 186777600);
    unsigned short* WoutTbf = (unsigned short*)(ws + 188006400);
    unsigned char*  wmask   = (unsigned char*)(ws + 188399616);
    float*          biasC   = (float*)(ws + 188450816);
    float*          dvec    = (float*)(ws + 188453888);
    unsigned short* Gbf     = Abf;    // R0: A dead after gemm1

    prep1<<<2048, 256, 0, stream>>>(inputs, fix_seq, emb, Wih, Wout, bih, bhh,
                                    Abf, Wihbf, WoutTbf, biasC);
    gemm_bt128<<<400 * 6, 256, 0, stream>>>(Abf, Wihbf, biasC, xgbf, MROWS, G3H, KIN);
    gemmG_f32<<<400, 512, 0, stream>>>(fwe, WoutTbf, bout, Gbf, wmask, dvec);
    gru_scan<<<256, 512, 0, stream>>>(xgbf, Whh, bhh, lengths, hout);
    logits_dur<<<12800, 256, 0, stream>>>(hout, Gbf, fix_seq, wmask, dvec, Wdur, bdur, out);
}

// Round 16
// 461.280 us; speedup vs baseline: 1.1248x; 1.0047x over previous
//
#include <hip/hip_runtime.h>
#include <hip/hip_bf16.h>

typedef __attribute__((ext_vector_type(8))) short bf16x8;   // 8 bf16 in 4 VGPRs
typedef __attribute__((ext_vector_type(4))) float f32x4;    // MFMA accumulator
typedef __attribute__((ext_vector_type(4))) int   i32x4;

#define NB 256
#define NT 200
#define NW 200
#define NE 768
#define NH 256
#define NEMB 32
#define KIN 800           // E + EMB
#define G3H 768           // 3*H
#define MROWS 51200       // B*T

__device__ __forceinline__ float bf2f(unsigned short h) {
    return __uint_as_float(((unsigned)h) << 16);
}
__device__ __forceinline__ unsigned short f2bf(float f) {
    unsigned u = __float_as_uint(f);
    u += 0x7fff + ((u >> 16) & 1);   // RNE
    return (unsigned short)(u >> 16);
}
__device__ __forceinline__ float sigm(float x) { return 1.0f / (1.0f + __expf(-x)); }
__device__ __forceinline__ float tanh_fast(float x) {
    float e = __expf(2.0f * x);
    return 1.0f - 2.0f / (e + 1.0f);
}

#if __has_builtin(__builtin_amdgcn_sdot4)
__device__ __forceinline__ int SDOT4(int a, int b, int c) {
    return __builtin_amdgcn_sdot4(a, b, c, false);
}
#else
__device__ __forceinline__ int SDOT4(int a, int b, int c) {   // exact fallback
    #pragma unroll
    for (int j = 0; j < 4; j++)
        c += (int)(signed char)(a >> (8 * j)) * (int)(signed char)(b >> (8 * j));
    return c;
}
#endif

// async global->LDS, 16 B/lane. LDS dest: wave-uniform base + lane*16.
__device__ __forceinline__ void gload16(const void* g, void* l) {
    __builtin_amdgcn_global_load_lds((const __attribute__((address_space(1))) unsigned int*)g,
                                     (__attribute__((address_space(3))) unsigned int*)l,
                                     16, 0, 0);
}

// ---------------------------------------------------------------------------
// prep1: A_bf16[51200][800] = [bf16(inputs) | bf16(emb_table[fix])],
//        W_ih -> bf16 [768][800], W_out -> bf16 TRANSPOSED [256][768],
//        biasC[768] = b_ih + (row<512 ? b_hh : 0).
// Div-free decomposition: unit u -> row = u>>7, chunk c = u&127 (c>=100/96
// skipped) — the old u/100, u%100 was a 64-bit int division per unit, pure
// VALU overhead on a memory-bound kernel.
// ---------------------------------------------------------------------------
__global__ void prep1(const float* __restrict__ inputs, const int* __restrict__ fix_seq,
                      const float* __restrict__ emb, const float* __restrict__ Wih,
                      const float* __restrict__ Wout, const float* __restrict__ bih,
                      const float* __restrict__ bhh,
                      unsigned short* __restrict__ Abf, unsigned short* __restrict__ Wihbf,
                      unsigned short* __restrict__ WoutTbf, float* __restrict__ biasC) {
    const long gid0 = (long)blockIdx.x * blockDim.x + threadIdx.x;
    if (gid0 < G3H) biasC[gid0] = bih[gid0] + (gid0 < 512 ? bhh[gid0] : 0.0f);
    const long NA = (long)MROWS << 7;    // 128 slots/row, 100 active
    const long NWU = 768L << 7;          // 128 slots/row, 100 active
    const long NOU = 256L << 7;          // 128 slots/row, 96 active
    const long total = NA + NWU + NOU;
    for (long u = gid0; u < total; u += (long)gridDim.x * blockDim.x) {
        bf16x8 v;
        unsigned short* dst;
        if (u < NA) {
            const long row = u >> 7;
            const int c = (int)(u & 127);
            if (c >= 100) continue;
            const int c8 = c << 3;
            const float* s;
            if (c8 < NE) {
                s = inputs + row * NE + c8;
            } else {
                int fx = fix_seq[row];
                s = emb + (long)fx * NEMB + (c8 - NE);
            }
            #pragma unroll
            for (int j = 0; j < 8; j++) v[j] = (short)f2bf(s[j]);
            dst = Abf + row * KIN + c8;
        } else if (u < NA + NWU) {
            const long u2 = u - NA;
            const long row = u2 >> 7;
            const int c = (int)(u2 & 127);
            if (c >= 100) continue;
            const int c8 = c << 3;
            const float* s = Wih + row * KIN + c8;
            #pragma unroll
            for (int j = 0; j < 8; j++) v[j] = (short)f2bf(s[j]);
            dst = Wihbf + row * KIN + c8;
        } else {
            const long u3 = u - NA - NWU;
            const long row = u3 >> 7;            // h index 0..255
            const int c = (int)(u3 & 127);
            if (c >= 96) continue;
            const int c8 = c << 3;               // e chunk
            #pragma unroll
            for (int j = 0; j < 8; j++)
                v[j] = (short)f2bf(Wout[(long)(c8 + j) * NH + row]);   // transpose gather
            dst = WoutTbf + row * NE + c8;
        }
        *(bf16x8*)dst = v;
    }
}

// ---------------------------------------------------------------------------
// gemm_bt128: Out[M][N] (bf16) = A[M][K](bf16) * Bw[N][K](bf16)^T + bias
// BM=128, BN=256 (A re-reads halved vs BN=128: was 6 N-tile blocks re-staging
// the same A-panel -> 490 MB L2/L3 A traffic; now 3), BK=32, 512 threads
// (8 waves = 2Mx4N of 64x64). T4 counted-vmcnt(3) pipeline, gload16, XCD
// swizzle. Requires M%128==0, N%256==0, K%32==0. Same K accumulation order
// as R14 -> bit-identical outputs.
// ---------------------------------------------------------------------------
__global__ __launch_bounds__(512, 4)
void gemm_bt128(const unsigned short* __restrict__ A,
                const unsigned short* __restrict__ Bw,
                const float* __restrict__ bias,
                unsigned short* __restrict__ Out,
                int M, int N, int K) {
    __shared__ unsigned short As[2][128 * 32];   // 2 x 8 KB
    __shared__ unsigned short Bs[2][256 * 32];   // 2 x 16 KB
    const int bid = (int)((blockIdx.x & 7) * (gridDim.x >> 3) + (blockIdx.x >> 3));
    const int nblk = N >> 8;
    const int m0 = (bid / nblk) << 7;
    const int n0 = (bid % nblk) << 8;
    const int tid = threadIdx.x;
    const int lane = tid & 63;
    const int wave = tid >> 6;
    const int wm = (wave >> 2) << 6;     // 0 / 64
    const int wn = (wave & 3) << 6;      // 0 / 64 / 128 / 192
    const int nk = K >> 5;

    const int srow = tid >> 2;           // 0..127
    const int sseg = (tid & 3) << 4;
    const char* gA  = (const char*)(A + (long)(m0 + srow) * K) + sseg;
    const char* gB0 = (const char*)(Bw + (long)(n0 + srow) * K) + sseg;
    const char* gB1 = (const char*)(Bw + (long)(n0 + 128 + srow) * K) + sseg;
    const int lofs = wave * 1024;        // 512 thr x 16 B = one 8 KB gload span

    f32x4 acc[4][4] = {};

    // prologue: stage tile 0 (3 loads in flight)
    gload16(gA,  (char*)As[0] + lofs);
    gload16(gB0, (char*)Bs[0] + lofs);
    gload16(gB1, (char*)Bs[0] + 8192 + lofs);

    int cur = 0;
    for (int kt = 0; kt < nk; kt++) {
        if (kt + 1 < nk) {               // stage NEXT tile; stays in flight past barrier
            gload16(gA  + (kt + 1) * 64, (char*)As[cur ^ 1] + lofs);
            gload16(gB0 + (kt + 1) * 64, (char*)Bs[cur ^ 1] + lofs);
            gload16(gB1 + (kt + 1) * 64, (char*)Bs[cur ^ 1] + 8192 + lofs);
            asm volatile("s_waitcnt vmcnt(3)" ::: "memory");   // oldest 3 (= buf[cur]) done
        } else {
            asm volatile("s_waitcnt vmcnt(0)" ::: "memory");   // last tile: drain
        }
        __builtin_amdgcn_sched_barrier(0);
        __builtin_amdgcn_s_barrier();      // all waves' buf[cur] stage-writes visible
        __builtin_amdgcn_sched_barrier(0);
        bf16x8 af[4], bfr[4];
        #pragma unroll
        for (int mi = 0; mi < 4; mi++)
            af[mi] = *(const bf16x8*)((const char*)As[cur] +
                        (wm + mi * 16 + (lane & 15)) * 64 + ((lane >> 4) << 4));
        #pragma unroll
        for (int ni = 0; ni < 4; ni++)
            bfr[ni] = *(const bf16x8*)((const char*)Bs[cur] +
                        (wn + ni * 16 + (lane & 15)) * 64 + ((lane >> 4) << 4));
        #pragma unroll
        for (int mi = 0; mi < 4; mi++)
            #pragma unroll
            for (int ni = 0; ni < 4; ni++)
                acc[mi][ni] = __builtin_amdgcn_mfma_f32_16x16x32_bf16(
                                  af[mi], bfr[ni], acc[mi][ni], 0, 0, 0);
        // WAR: this wave's ds_reads retired, then block-wide barrier before
        // buf[cur] is overwritten next iteration. No vmcnt drain here.
        asm volatile("s_waitcnt lgkmcnt(0)" ::: "memory");
        __builtin_amdgcn_sched_barrier(0);
        __builtin_amdgcn_s_barrier();
        __builtin_amdgcn_sched_barrier(0);
        cur ^= 1;
    }
    // epilogue: D col = lane&15, row = (lane>>4)*4 + r  (m89-verified layout)
    #pragma unroll
    for (int ni = 0; ni < 4; ni++) {
        const int col = n0 + wn + ni * 16 + (lane & 15);
        const float bv = bias[col];
        #pragma unroll
        for (int mi = 0; mi < 4; mi++) {
            const int row = m0 + wm + mi * 16 + ((lane >> 4) << 2);
            #pragma unroll
            for (int r = 0; r < 4; r++)
                Out[(long)(row + r) * N + col] = f2bf(acc[mi][ni][r] + bv);
        }
    }
}

// ---------------------------------------------------------------------------
// gemmG_f32: G[M][256] = fwe[M][768](fp32) @ WoutT[256][768](bf16)^T.
// BN = 256 (full N per block) -> fwe read exactly once. (R15 form, frozen.)
// ---------------------------------------------------------------------------
__global__ __launch_bounds__(512)
void gemmG_f32(const float* __restrict__ fwe,           // [51200][768] fp32
               const unsigned short* __restrict__ BwT,  // WoutT [256][768] bf16
               const float* __restrict__ bout,          // [768]
               unsigned short* __restrict__ G,          // [51200][256] bf16
               unsigned char* __restrict__ wmask,       // [51200]
               float* __restrict__ dvec) {              // [51200]
    __shared__ unsigned short As[128 * 32];   //  8 KB
    __shared__ unsigned short Bs[256 * 32];   // 16 KB
    __shared__ float Bo[G3H];                 //  3 KB
    const int m0 = (int)blockIdx.x << 7;
    const int tid = threadIdx.x;
    const int lane = tid & 63;
    const int wave = tid >> 6;
    const int wm = (wave >> 2) << 6;     // 0 / 64
    const int wn = (wave & 3) << 6;      // 0 / 64 / 128 / 192

    // A reg-staging: row = tid>>2 (0..127), k-quarter kq = tid&3 (8 floats)
    const int arow = tid >> 2;
    const int akq = tid & 3;
    const float* aptr = fwe + (long)(m0 + arow) * NE + akq * 8;
    char* la = (char*)As + arow * 64 + akq * 16;

    // B staging (gload16, 2 rounds): thread -> row tid>>2 (+128), seg tid&3
    const int sseg = (tid & 3) << 4;
    const char* gBa = (const char*)(BwT + (long)arow * NE) + sseg;          // rows 0-127
    const char* gBb = (const char*)(BwT + (long)(128 + arow) * NE) + sseg;  // rows 128-255
    char* lBa = (char*)Bs + wave * 1024;
    char* lBb = (char*)Bs + 8192 + wave * 1024;

    for (int i = tid; i < G3H; i += 512) Bo[i] = bout[i];

    float4 fa0 = *(const float4*)(aptr);
    float4 fa1 = *(const float4*)(aptr + 4);

    f32x4 acc[4][4] = {};
    float asum = 0.0f, vdot = 0.0f;

    __syncthreads();                     // Bo visible

    for (int kt = 0; kt < 24; kt++) {    // K = 768
        __syncthreads();                 // previous tile's LDS reads complete
        gload16(gBa + kt * 64, lBa);
        gload16(gBb + kt * 64, lBb);
        // fold reductions (fp32, pre-conversion), convert + write A slice
        const float* bo = Bo + kt * 32 + akq * 8;
        const float4 b0 = *(const float4*)(bo);
        const float4 b1 = *(const float4*)(bo + 4);
        asum += fabsf(fa0.x) + fabsf(fa0.y) + fabsf(fa0.z) + fabsf(fa0.w)
              + fabsf(fa1.x) + fabsf(fa1.y) + fabsf(fa1.z) + fabsf(fa1.w);
        vdot += fa0.x * b0.x + fa0.y * b0.y + fa0.z * b0.z + fa0.w * b0.w
              + fa1.x * b1.x + fa1.y * b1.y + fa1.z * b1.z + fa1.w * b1.w;
        bf16x8 v;
        v[0] = (short)f2bf(fa0.x); v[1] = (short)f2bf(fa0.y);
        v[2] = (short)f2bf(fa0.z); v[3] = (short)f2bf(fa0.w);
        v[4] = (short)f2bf(fa1.x); v[5] = (short)f2bf(fa1.y);
        v[6] = (short)f2bf(fa1.z); v[7] = (short)f2bf(fa1.w);
        *(bf16x8*)la = v;
        asm volatile("s_waitcnt vmcnt(0)" ::: "memory");   // B landed
        __syncthreads();                 // all stages visible (incl. ds_writes)
        if (kt + 1 < 24) {               // A prefetch hides under MFMA phase
            const float* ap = aptr + (kt + 1) * 32;
            fa0 = *(const float4*)(ap);
            fa1 = *(const float4*)(ap + 4);
        }
        bf16x8 af[4], bfr[4];
        #pragma unroll
        for (int mi = 0; mi < 4; mi++)
            af[mi] = *(const bf16x8*)((const char*)As +
                        (wm + mi * 16 + (lane & 15)) * 64 + ((lane >> 4) << 4));
        #pragma unroll
        for (int ni = 0; ni < 4; ni++)
            bfr[ni] = *(const bf16x8*)((const char*)Bs +
                        (wn + ni * 16 + (lane & 15)) * 64 + ((lane >> 4) << 4));
        #pragma unroll
        for (int mi = 0; mi < 4; mi++)
            #pragma unroll
            for (int ni = 0; ni < 4; ni++)
                acc[mi][ni] = __builtin_amdgcn_mfma_f32_16x16x32_bf16(
                                  af[mi], bfr[ni], acc[mi][ni], 0, 0, 0);
    }
    // reductions: combine the row's 4 k-quarter threads (consecutive lanes)
    asum += __shfl_xor(asum, 1);  asum += __shfl_xor(asum, 2);
    vdot += __shfl_xor(vdot, 1);  vdot += __shfl_xor(vdot, 2);
    if (akq == 0) {
        wmask[m0 + arow] = (asum != 0.0f) ? 1 : 0;
        dvec[m0 + arow] = vdot;
    }
    // G epilogue (no bias)
    #pragma unroll
    for (int ni = 0; ni < 4; ni++) {
        const int col = wn + ni * 16 + (lane & 15);
        #pragma unroll
        for (int mi = 0; mi < 4; mi++) {
            const int row = m0 + wm + mi * 16 + ((lane >> 4) << 2);
            #pragma unroll
            for (int r = 0; r < 4; r++)
                G[(long)(row + r) * NH + col] = f2bf(acc[mi][ni][r]);
        }
    }
}

// ---------------------------------------------------------------------------
// gru_scan: 256 blocks (1 batch each), 512 threads (8 waves, 2/SIMD).
// Pure-VALU int8 GEMV via v_dot4_i32_i8 (R7/R8 structure, unchanged).
// ---------------------------------------------------------------------------
__global__ __launch_bounds__(512, 2)
__attribute__((amdgpu_waves_per_eu(2, 2)))
void gru_scan(const unsigned short* __restrict__ xg,   // [51200][768] bf16 (incl biasC)
              const float* __restrict__ Whh,            // [768][256] fp32
              const float* __restrict__ bhh,            // [768]
              const int* __restrict__ lengths,          // [256]
              unsigned short* __restrict__ hout) {      // [51200][256] bf16 (masked)
    __shared__ __align__(16) unsigned char h8[2][256];  // int8 h double buffer
    const int tid = threadIdx.x;
    const int lane = tid & 63;
    const int wave = tid >> 6;               // 0..7
    const int b = blockIdx.x;
    const int col = wave * 32 + (lane & 31); // this thread's h-col
    const int kh = lane >> 5;                // K-half 0/1

    int W[3][32];
    #pragma unroll
    for (int g = 0; g < 3; g++) {
        const float* wr = Whh + (long)(g * 256 + col) * NH + kh * 128;
        #pragma unroll
        for (int d = 0; d < 32; d++) {
            const float4 f = *(const float4*)(wr + d * 4);
            unsigned pack = 0;
            #pragma unroll
            for (int j = 0; j < 4; j++) {
                const float fv = j == 0 ? f.x : j == 1 ? f.y : j == 2 ? f.z : f.w;
                int wq = (int)rintf(fv * 400.0f);
                wq = wq > 127 ? 127 : (wq < -127 ? -127 : wq);
                pack |= ((unsigned)(wq & 0xff)) << (8 * j);
            }
            W[g][d] = (int)pack;
        }
    }
    const float bhn = bhh[512 + col];        // n-gate b_hh (r,z folded into xg)
    const int len = lengths[b];
    if (tid < 128) ((unsigned*)h8)[tid] = 0u;   // zero both h buffers (512 B)

    const unsigned short* xrow = xg + (long)b * NT * G3H;
    unsigned short xv0 = xrow[col], xv1 = xrow[256 + col], xv2 = xrow[512 + col];
    float hp = 0.0f;
    const float ISC = 1.0f / (400.0f * 127.0f);
    const bool wlo = (lane < 32);

    asm volatile("s_waitcnt lgkmcnt(0)" ::: "memory");
    __builtin_amdgcn_sched_barrier(0);
    __builtin_amdgcn_s_barrier();
    __builtin_amdgcn_sched_barrier(0);

    for (int t = 0; t < NT; t++) {
        const unsigned char* hb = h8[(t + 1) & 1] + kh * 128;
        int p0a = 0, p0b = 0, p1a = 0, p1b = 0, p2a = 0, p2b = 0;
        #pragma unroll
        for (int r = 0; r < 8; r++) {
            const i32x4 hv = *(const i32x4*)(hb + r * 16);
            p0a = SDOT4(hv[0], W[0][r * 4 + 0], p0a);
            p1a = SDOT4(hv[0], W[1][r * 4 + 0], p1a);
            p2a = SDOT4(hv[0], W[2][r * 4 + 0], p2a);
            p0b = SDOT4(hv[1], W[0][r * 4 + 1], p0b);
            p1b = SDOT4(hv[1], W[1][r * 4 + 1], p1b);
            p2b = SDOT4(hv[1], W[2][r * 4 + 1], p2b);
            p0a = SDOT4(hv[2], W[0][r * 4 + 2], p0a);
            p1a = SDOT4(hv[2], W[1][r * 4 + 2], p1a);
            p2a = SDOT4(hv[2], W[2][r * 4 + 2], p2a);
            p0b = SDOT4(hv[3], W[0][r * 4 + 3], p0b);
            p1b = SDOT4(hv[3], W[1][r * 4 + 3], p1b);
            p2b = SDOT4(hv[3], W[2][r * 4 + 3], p2b);
        }
        int p0 = p0a + p0b, p1 = p1a + p1b, p2 = p2a + p2b;
        p0 += __shfl_xor(p0, 32);            // combine K-halves
        p1 += __shfl_xor(p1, 32);
        p2 += __shfl_xor(p2, 32);
        const float r = sigm(bf2f(xv0) + (float)p0 * ISC);
        const float z = sigm(bf2f(xv1) + (float)p1 * ISC);
        const float n = tanh_fast(bf2f(xv2) + r * ((float)p2 * ISC + bhn));
        hp = (1.0f - z) * n + z * hp;
        if (wlo) {
            h8[t & 1][col] = (unsigned char)((int)rintf(hp * 127.0f) & 0xff);
            hout[((long)b * NT + t) * NH + col] = (t < len) ? f2bf(hp) : (unsigned short)0;
        }
        if (t + 1 < NT) {
            const unsigned short* xn = xrow + (long)(t + 1) * G3H;
            xv0 = xn[col]; xv1 = xn[256 + col]; xv2 = xn[512 + col];
        }
        asm volatile("s_waitcnt lgkmcnt(0)" ::: "memory");
        __builtin_amdgcn_sched_barrier(0);
        __builtin_amdgcn_s_barrier();
        __builtin_amdgcn_sched_barrier(0);
    }
}

// ---------------------------------------------------------------------------
// logits_dur: wave per (b,t) row; only |w-fix|<=8 dots computed; dur fused.
// (R11 form, unchanged.)
// ---------------------------------------------------------------------------
__global__ __launch_bounds__(256)
void logits_dur(const unsigned short* __restrict__ Hrow,   // hout [51200][256]
                const unsigned short* __restrict__ G,      // [51200][256]
                const int* __restrict__ fix_seq,           // [51200]
                const unsigned char* __restrict__ wmask,   // [51200]
                const float* __restrict__ dvec,            // [51200]
                const float* __restrict__ Wdur, const float* __restrict__ bdur,
                float* __restrict__ out) {
    __shared__ float dots[4][20];
    const int wv = threadIdx.x >> 6;
    const int gwave = (int)blockIdx.x * 4 + wv;            // 0..51199 = b*200+t
    const int lane = threadIdx.x & 63;
    const int l16 = lane & 15;
    const int grp = lane >> 4;                              // 0..3
    const int b = gwave / NT;

    const unsigned short* hp = Hrow + (long)gwave * NH + l16 * 16;
    const bf16x8 h0 = *(const bf16x8*)hp;
    const bf16x8 h1 = *(const bf16x8*)(hp + 8);
    float hf[16];
    #pragma unroll
    for (int j = 0; j < 8; j++) { hf[j] = bf2f((unsigned short)h0[j]);
                                  hf[8 + j] = bf2f((unsigned short)h1[j]); }

    const int fix = fix_seq[gwave];
    const int wbase = fix - 8;

    if (fix != 0) {
        #pragma unroll
        for (int it = 0; it < 5; it++) {
            const int wi = it * 4 + grp;                    // 0..19 (17..19 unused)
            int w = wbase + wi;
            w = w < 0 ? 0 : (w > NW - 1 ? NW - 1 : w);      // clamp for safe load
            const unsigned short* gp = G + ((long)b * NW + w) * NH + l16 * 16;
            const bf16x8 g0 = *(const bf16x8*)gp;
            const bf16x8 g1 = *(const bf16x8*)(gp + 8);
            float p = 0.0f;
            #pragma unroll
            for (int j = 0; j < 8; j++) {
                p += hf[j] * bf2f((unsigned short)g0[j]);
                p += hf[8 + j] * bf2f((unsigned short)g1[j]);
            }
            p += __shfl_xor(p, 1); p += __shfl_xor(p, 2);
            p += __shfl_xor(p, 4); p += __shfl_xor(p, 8);
            if (l16 == 0 && wi < 17) dots[wv][wi] = p;
        }
    }
    float pd = 0.0f;
    #pragma unroll
    for (int j = 0; j < 16; j++) pd += hf[j] * Wdur[l16 * 16 + j];
    pd += __shfl_xor(pd, 1); pd += __shfl_xor(pd, 2);
    pd += __shfl_xor(pd, 4); pd += __shfl_xor(pd, 8);
    if (lane == 0) out[(long)NB * NT * NW + gwave] = pd + bdur[0];

    __syncthreads();

    if (lane < 50) {
        float4 o;
        #pragma unroll
        for (int c = 0; c < 4; c++) {
            const int w = lane * 4 + c;
            const int wi = w - wbase;
            const int wic = wi < 0 ? 0 : (wi > 16 ? 16 : wi);
            const bool ok = (fix != 0) && ((unsigned)wi < 17u) && (wmask[b * NW + w] != 0);
            const float val = dots[wv][wic] + dvec[b * NW + w];
            ((float*)&o)[c] = ok ? val : -1e9f;
        }
        *(float4*)(out + (long)gwave * NW + lane * 4) = o;
    }
}

// ---------------------------------------------------------------------------
extern "C" void kernel_launch(void* const* d_in, const int* in_sizes, int n_in,
                              void* d_out, int out_size, void* d_ws, size_t ws_size,
                              hipStream_t stream) {
    (void)in_sizes; (void)n_in; (void)out_size; (void)ws_size;
    const float* inputs  = (const float*)d_in[0];
    const int*   fix_seq = (const int*)d_in[1];
    const float* fwe     = (const float*)d_in[2];
    const int*   lengths = (const int*)d_in[3];
    const float* emb     = (const float*)d_in[5];
    const float* Wih     = (const float*)d_in[6];
    const float* bih     = (const float*)d_in[7];
    const float* Whh     = (const float*)d_in[8];
    const float* bhh     = (const float*)d_in[9];
    const float* Wout    = (const float*)d_in[10];
    const float* bout    = (const float*)d_in[11];
    const float* Wdur    = (const float*)d_in[12];
    const float* bdur    = (const float*)d_in[13];
    float* out = (float*)d_out;

    char* ws = (char*)d_ws;
    // region layout (bytes, all 256-aligned):
    //   R0 [0, 81,920,000)            A_bf16 [51200][800]  -> G [51200][256] after gemm1
    //   R1 [81,920,000, +78,643,200)  xg_bf16 [51200][768]
    //   R2 [160,563,200, +26,214,400) hout_bf16 [51200][256]
    //   [186,777,600, +1,228,800)     W_ih bf16
    //   [188,006,400, +393,216)       W_outT bf16 [256][768]
    //   [188,399,616, +51,200)        word_mask u8
    //   [188,450,816, +3,072)         biasC f32 [768]
    //   [188,453,888, +204,800)       dvec f32 [51200]
    unsigned short* Abf     = (unsigned short*)(ws);
    unsigned short* xgbf    = (unsigned short*)(ws + 81920000);
    unsigned short* hout    = (unsigned short*)(ws + 160563200);
    unsigned short* Wihbf   = (unsigned short*)(ws + 186777600);
    unsigned short* WoutTbf = (unsigned short*)(ws + 188006400);
    unsigned char*  wmask   = (unsigned char*)(ws + 188399616);
    float*          biasC   = (float*)(ws + 188450816);
    float*          dvec    = (float*)(ws + 188453888);
    unsigned short* Gbf     = Abf;    // R0: A dead after gemm1

    prep1<<<2048, 256, 0, stream>>>(inputs, fix_seq, emb, Wih, Wout, bih, bhh,
                                    Abf, Wihbf, WoutTbf, biasC);
    gemm_bt128<<<400 * 3, 512, 0, stream>>>(Abf, Wihbf, biasC, xgbf, MROWS, G3H, KIN);
    gemmG_f32<<<400, 512, 0, stream>>>(fwe, WoutTbf, bout, Gbf, wmask, dvec);
    gru_scan<<<256, 512, 0, stream>>>(xgbf, Whh, bhh, lengths, hout);
    logits_dur<<<12800, 256, 0, stream>>>(hout, Gbf, fix_seq, wmask, dvec, Wdur, bdur, out);
}